// Round 1
// baseline (3019.566 us; speedup 1.0000x reference)
//
#include <hip/hip_runtime.h>
#include <hip/hip_bf16.h>

// ---------------------------------------------------------------------------
// Sizes (fixed by the problem)
// ---------------------------------------------------------------------------
#define B 256
#define C1H 30           // after conv1: [B,64,30,30]
#define C2H 15           // after conv2: [B,64,15,15]
#define FH 7             // ODE state: [B,64,7,7]
#define NCH 64
#define NPIX (FH*FH)     // 49
#define NELEM (NCH*NPIX) // 3136 per image
#define TOTAL (B*NELEM)  // 802816

// LDS padded layout for f-eval: [65 channels][9][9] (ch 0 = t channel)
#define LDW 9
#define LDCH 81          // 9*9
#define LDSZ (65*LDCH+32)

// ---------------------------------------------------------------------------
// conv1: x[256,3,32,32] -> h1[256,64,30,30], 3x3 s1 p0 (raw, no GN)
// ---------------------------------------------------------------------------
__global__ __launch_bounds__(256) void conv1_kernel(
    const float* __restrict__ x, const float* __restrict__ w,
    const float* __restrict__ bias, float* __restrict__ out)
{
    __shared__ float sw[64*27];
    __shared__ float sb[64];
    const int t = threadIdx.x;
    for (int i = t; i < 64*27; i += 256) sw[i] = w[i];
    if (t < 64) sb[t] = bias[t];
    __syncthreads();

    const int pid = blockIdx.x * 256 + t;       // < 256*900
    const int b  = pid / 900;
    const int p  = pid % 900;
    const int oy = p / 30, ox = p % 30;

    float xv[27];
    #pragma unroll
    for (int c = 0; c < 3; ++c)
        #pragma unroll
        for (int ky = 0; ky < 3; ++ky)
            #pragma unroll
            for (int kx = 0; kx < 3; ++kx)
                xv[c*9 + ky*3 + kx] = x[((b*3 + c)*32 + oy + ky)*32 + ox + kx];

    for (int oc = 0; oc < 64; ++oc) {
        float acc = sb[oc];
        #pragma unroll
        for (int j = 0; j < 27; ++j) acc = fmaf(sw[oc*27 + j], xv[j], acc);
        out[(b*64 + oc)*900 + p] = acc;
    }
}

// ---------------------------------------------------------------------------
// Generic GN stats: one block (1 wave) per (b, group); 2 channels per group
// ---------------------------------------------------------------------------
__global__ __launch_bounds__(64) void gn_stats_kernel(
    const float* __restrict__ x, int HW, float* __restrict__ mean,
    float* __restrict__ rstd)
{
    const int bg = blockIdx.x;              // b*32 + g
    const int lane = threadIdx.x;           // 0..63
    const float* p = x + (size_t)bg * 2 * HW;
    const int N = 2 * HW;
    float s = 0.f, sq = 0.f;
    for (int i = lane; i < N; i += 64) {
        float v = p[i];
        s += v; sq += v*v;
    }
    #pragma unroll
    for (int off = 1; off < 64; off <<= 1) {
        s  += __shfl_xor(s, off);
        sq += __shfl_xor(sq, off);
    }
    if (lane == 0) {
        float m = s / (float)N;
        float var = sq / (float)N - m*m;
        mean[bg] = m;
        rstd[bg] = rsqrtf(var + 1e-5f);
    }
}

// ---------------------------------------------------------------------------
// GN apply + ReLU in place
// ---------------------------------------------------------------------------
__global__ __launch_bounds__(256) void gn_apply_kernel(
    float* __restrict__ x, const float* __restrict__ mean,
    const float* __restrict__ rstd, const float* __restrict__ gw,
    const float* __restrict__ gb, int HW, int total)
{
    const int stride = gridDim.x * 256;
    for (int i = blockIdx.x*256 + threadIdx.x; i < total; i += stride) {
        int c  = (i / HW) & 63;
        int bg = i / (HW * 2);
        float v = x[i];
        v = (v - mean[bg]) * rstd[bg] * gw[c] + gb[c];
        x[i] = fmaxf(v, 0.f);
    }
}

// ---------------------------------------------------------------------------
// conv2: h1n[256,64,30,30] -> h2[256,64,15,15], 4x4 s2 p1
// grid (225, 8): blockIdx.y selects 8 output channels
// ---------------------------------------------------------------------------
__global__ __launch_bounds__(256) void conv2_kernel(
    const float* __restrict__ in, const float* __restrict__ w,
    const float* __restrict__ bias, float* __restrict__ out)
{
    const int t = threadIdx.x;
    const int pid = blockIdx.x * 256 + t;   // < 256*225
    const int b = pid / 225, p = pid % 225;
    const int oy = p / 15, ox = p % 15;
    const int oc0 = blockIdx.y * 8;
    const int iy0 = oy*2 - 1, ix0 = ox*2 - 1;

    float acc[8];
    #pragma unroll
    for (int j = 0; j < 8; ++j) acc[j] = 0.f;

    for (int c = 0; c < 64; ++c) {
        const float* ib = in + ((size_t)(b*64 + c))*900;
        const float* wb = w + (size_t)oc0*1024 + c*16;
        #pragma unroll
        for (int ky = 0; ky < 4; ++ky) {
            int iy = iy0 + ky;
            if (iy < 0 || iy >= 30) continue;
            #pragma unroll
            for (int kx = 0; kx < 4; ++kx) {
                int ix = ix0 + kx;
                if (ix < 0 || ix >= 30) continue;
                float v = ib[iy*30 + ix];
                #pragma unroll
                for (int j = 0; j < 8; ++j)
                    acc[j] = fmaf(v, wb[j*1024 + ky*4 + kx], acc[j]);
            }
        }
    }
    #pragma unroll
    for (int j = 0; j < 8; ++j)
        out[((size_t)(b*64 + oc0 + j))*225 + p] = acc[j] + bias[oc0 + j];
}

// ---------------------------------------------------------------------------
// conv3: h2n[256,64,15,15] -> y[256,64,7,7], 4x4 s2 p1
// ---------------------------------------------------------------------------
__global__ __launch_bounds__(256) void conv3_kernel(
    const float* __restrict__ in, const float* __restrict__ w,
    const float* __restrict__ bias, float* __restrict__ out)
{
    const int t = threadIdx.x;
    const int pid = blockIdx.x * 256 + t;   // < 256*49
    const int b = pid / 49, p = pid % 49;
    const int oy = p / 7, ox = p % 7;
    const int oc0 = blockIdx.y * 8;
    const int iy0 = oy*2 - 1, ix0 = ox*2 - 1;

    float acc[8];
    #pragma unroll
    for (int j = 0; j < 8; ++j) acc[j] = 0.f;

    for (int c = 0; c < 64; ++c) {
        const float* ib = in + ((size_t)(b*64 + c))*225;
        const float* wb = w + (size_t)oc0*1024 + c*16;
        #pragma unroll
        for (int ky = 0; ky < 4; ++ky) {
            int iy = iy0 + ky;
            if (iy < 0 || iy >= 15) continue;
            #pragma unroll
            for (int kx = 0; kx < 4; ++kx) {
                int ix = ix0 + kx;
                if (ix < 0 || ix >= 15) continue;
                float v = ib[iy*15 + ix];
                #pragma unroll
                for (int j = 0; j < 8; ++j)
                    acc[j] = fmaf(v, wb[j*1024 + ky*4 + kx], acc[j]);
            }
        }
    }
    #pragma unroll
    for (int j = 0; j < 8; ++j)
        out[((size_t)(b*64 + oc0 + j))*49 + p] = acc[j] + bias[oc0 + j];
}

// ---------------------------------------------------------------------------
// f-eval helpers (device, operate on per-image LDS buffers)
// ---------------------------------------------------------------------------
__device__ __forceinline__ int lds_addr(int ch_model, int pix) {
    // model channel c -> LDS channel c+1; pixel -> padded interior
    return (ch_model + 1)*LDCH + (pix/7 + 1)*LDW + (pix%7 + 1);
}

// stats over LDS buffer, 32 groups x 16 threads (512-thread block)
__device__ __forceinline__ void gn_stats_lds(
    const float* buf, float* s_mean, float* s_rstd, int t)
{
    const int g = t >> 4, sub = t & 15;
    float s = 0.f, sq = 0.f;
    for (int e = sub; e < 98; e += 16) {
        int ch = g*2 + (e >= 49 ? 1 : 0);
        int pix = (e >= 49) ? e - 49 : e;
        float v = buf[lds_addr(ch, pix)];
        s += v; sq += v*v;
    }
    s += __shfl_xor(s, 1);  sq += __shfl_xor(sq, 1);
    s += __shfl_xor(s, 2);  sq += __shfl_xor(sq, 2);
    s += __shfl_xor(s, 4);  sq += __shfl_xor(sq, 4);
    s += __shfl_xor(s, 8);  sq += __shfl_xor(sq, 8);
    if (sub == 0) {
        float m = s * (1.f/98.f);
        float var = sq * (1.f/98.f) - m*m;
        s_mean[g] = m;
        s_rstd[g] = rsqrtf(var + 1e-5f);
    }
}

__device__ __forceinline__ void gn_norm_lds(
    float* buf, const float* __restrict__ gw, const float* __restrict__ gb,
    const float* s_mean, const float* s_rstd, int t)
{
    for (int i = t; i < NELEM; i += 512) {
        int ch = i / 49, pix = i % 49;
        int ad = lds_addr(ch, pix);
        float v = buf[ad];
        int g = ch >> 1;
        v = (v - s_mean[g]) * s_rstd[g] * gw[ch] + gb[ch];
        buf[ad] = fmaxf(v, 0.f);
    }
}

// conv 65->64, 3x3 p1 from LDS src to LDS dst (raw, +bias).
// wave w handles output channels [w*8, w*8+8); lane = pixel (49 of 64 used)
__device__ __forceinline__ void conv_lds(
    const float* src, float* dst,
    const float* __restrict__ W, const float* __restrict__ Bb, int t)
{
    const int wave = __builtin_amdgcn_readfirstlane(t >> 6);  // 0..7, uniform
    const int lane = t & 63;
    const int oc0 = wave * 8;
    const int py = lane / 7, px = lane % 7;     // garbage for lane>=49, padded reads OK
    const int center = (py + 1)*LDW + (px + 1);

    float acc[8];
    #pragma unroll
    for (int j = 0; j < 8; ++j) acc[j] = 0.f;

    const float* wb = W + oc0 * 585;
    for (int ic = 0; ic < 65; ++ic) {
        const int ib = ic*LDCH + center;
        const float* wi = wb + ic*9;
        #pragma unroll
        for (int tp = 0; tp < 9; ++tp) {
            const int off = (tp/3 - 1)*LDW + (tp%3 - 1);
            float v = src[ib + off];
            #pragma unroll
            for (int j = 0; j < 8; ++j)
                acc[j] = fmaf(v, wi[j*585 + tp], acc[j]);
        }
    }
    if (lane < 49) {
        #pragma unroll
        for (int j = 0; j < 8; ++j)
            dst[(oc0 + j + 1)*LDCH + center] = acc[j] + Bb[oc0 + j];
    }
}

// ---------------------------------------------------------------------------
// Full f evaluation: kout = f(t, y + cA*kA + ... ), one block per image
// ---------------------------------------------------------------------------
__global__ __launch_bounds__(512) void f_eval_kernel(
    const float* __restrict__ ybase,
    const float* __restrict__ kA, const float* __restrict__ kB,
    const float* __restrict__ kC, const float* __restrict__ kD,
    const float* __restrict__ kE,
    float cA, float cB, float cC, float cD, float cE, int nk,
    float tval,
    const float* __restrict__ W1, const float* __restrict__ B1,
    const float* __restrict__ W2, const float* __restrict__ B2,
    const float* __restrict__ oa_w, const float* __restrict__ oa_b,
    const float* __restrict__ ob_w, const float* __restrict__ ob_b,
    const float* __restrict__ oc_w, const float* __restrict__ oc_b,
    float* __restrict__ kout)
{
    __shared__ float bufA[LDSZ];
    __shared__ float bufB[LDSZ];
    __shared__ float s_mean[32], s_rstd[32];

    const int t = threadIdx.x;
    const int b = blockIdx.x;
    const int boff = b * NELEM;

    // zero both buffers (borders must be 0)
    for (int i = t; i < LDSZ; i += 512) { bufA[i] = 0.f; bufB[i] = 0.f; }
    __syncthreads();

    // t-channel (LDS channel 0), interior only
    if (t < 49) {
        int ad = (t/7 + 1)*LDW + (t%7 + 1);
        bufA[ad] = tval;
        bufB[ad] = tval;
    }
    // stage input: y + sum c_j k_j  -> bufA channels 1..64
    for (int i = t; i < NELEM; i += 512) {
        float v = ybase[boff + i];
        if (nk > 0) v = fmaf(cA, kA[boff + i], v);
        if (nk > 1) v = fmaf(cB, kB[boff + i], v);
        if (nk > 2) v = fmaf(cC, kC[boff + i], v);
        if (nk > 3) v = fmaf(cD, kD[boff + i], v);
        if (nk > 4) v = fmaf(cE, kE[boff + i], v);
        bufA[lds_addr(i/49, i%49)] = v;
    }
    __syncthreads();

    // GN(oa) + ReLU on bufA
    gn_stats_lds(bufA, s_mean, s_rstd, t);
    __syncthreads();
    gn_norm_lds(bufA, oa_w, oa_b, s_mean, s_rstd, t);
    __syncthreads();

    // conv1 (65->64, includes t channel) -> bufB raw
    conv_lds(bufA, bufB, W1, B1, t);
    __syncthreads();

    // GN(ob) + ReLU on bufB
    gn_stats_lds(bufB, s_mean, s_rstd, t);
    __syncthreads();
    gn_norm_lds(bufB, ob_w, ob_b, s_mean, s_rstd, t);
    __syncthreads();

    // conv2 -> bufA raw (bufA contents dead now)
    conv_lds(bufB, bufA, W2, B2, t);
    __syncthreads();

    // GN(oc), no ReLU, write k out
    gn_stats_lds(bufA, s_mean, s_rstd, t);
    __syncthreads();
    for (int i = t; i < NELEM; i += 512) {
        int ch = i / 49;
        float v = bufA[lds_addr(ch, i % 49)];
        int g = ch >> 1;
        v = (v - s_mean[g]) * s_rstd[g] * oc_w[ch] + oc_b[ch];
        kout[boff + i] = v;
    }
}

// ---------------------------------------------------------------------------
// y += b1*k1 + b3*k3 + b4*k4 + b5*k5 + b6*k6   (coeffs include h)
// ---------------------------------------------------------------------------
__global__ __launch_bounds__(1024) void yupdate_kernel(
    float* __restrict__ y,
    const float* __restrict__ k1, const float* __restrict__ k3,
    const float* __restrict__ k4, const float* __restrict__ k5,
    const float* __restrict__ k6,
    float b1, float b3, float b4, float b5, float b6)
{
    int i = blockIdx.x * 1024 + threadIdx.x;   // grid sized exactly
    float v = y[i];
    v = fmaf(b1, k1[i], v);
    v = fmaf(b3, k3[i], v);
    v = fmaf(b4, k4[i], v);
    v = fmaf(b5, k5[i], v);
    v = fmaf(b6, k6[i], v);
    y[i] = v;
}

// ---------------------------------------------------------------------------
// head: GN(g3)+ReLU -> spatial mean -> linear [64 -> 10]; one block per image
// ---------------------------------------------------------------------------
__global__ __launch_bounds__(256) void head_kernel(
    const float* __restrict__ y,
    const float* __restrict__ g3_w, const float* __restrict__ g3_b,
    const float* __restrict__ lin_w, const float* __restrict__ lin_b,
    float* __restrict__ out)
{
    __shared__ float s_y[NELEM];
    __shared__ float s_mean[32], s_rstd[32];
    __shared__ float s_cm[64];
    const int t = threadIdx.x, b = blockIdx.x;

    for (int i = t; i < NELEM; i += 256) s_y[i] = y[b*NELEM + i];
    __syncthreads();

    {   // stats: 32 groups x 8 threads; group g = contiguous [g*98, g*98+98)
        const int g = t >> 3, sub = t & 7;
        float s = 0.f, sq = 0.f;
        for (int e = sub; e < 98; e += 8) {
            float v = s_y[g*98 + e];
            s += v; sq += v*v;
        }
        s += __shfl_xor(s, 1);  sq += __shfl_xor(sq, 1);
        s += __shfl_xor(s, 2);  sq += __shfl_xor(sq, 2);
        s += __shfl_xor(s, 4);  sq += __shfl_xor(sq, 4);
        if (sub == 0) {
            float m = s * (1.f/98.f);
            float var = sq * (1.f/98.f) - m*m;
            s_mean[g] = m;
            s_rstd[g] = rsqrtf(var + 1e-5f);
        }
    }
    __syncthreads();

    if (t < 64) {
        const int ch = t, g = ch >> 1;
        float m = s_mean[g], r = s_rstd[g];
        float w = g3_w[ch], bb = g3_b[ch];
        float sum = 0.f;
        for (int p = 0; p < 49; ++p) {
            float v = (s_y[ch*49 + p] - m) * r * w + bb;
            sum += fmaxf(v, 0.f);
        }
        s_cm[ch] = sum * (1.f/49.f);
    }
    __syncthreads();

    if (t < 10) {
        float a = lin_b[t];
        for (int c = 0; c < 64; ++c) a = fmaf(s_cm[c], lin_w[t*64 + c], a);
        out[b*10 + t] = a;
    }
}

// ---------------------------------------------------------------------------
// Host launch
// ---------------------------------------------------------------------------
extern "C" void kernel_launch(void* const* d_in, const int* in_sizes, int n_in,
                              void* d_out, int out_size, void* d_ws, size_t ws_size,
                              hipStream_t stream)
{
    const float* x      = (const float*)d_in[0];
    const float* c1_w   = (const float*)d_in[1];
    const float* c1_b   = (const float*)d_in[2];
    const float* g1_w   = (const float*)d_in[3];
    const float* g1_b   = (const float*)d_in[4];
    const float* c2_w   = (const float*)d_in[5];
    const float* c2_b   = (const float*)d_in[6];
    const float* g2_w   = (const float*)d_in[7];
    const float* g2_b   = (const float*)d_in[8];
    const float* c3_w   = (const float*)d_in[9];
    const float* c3_b   = (const float*)d_in[10];
    const float* oa_w   = (const float*)d_in[11];
    const float* oa_b   = (const float*)d_in[12];
    const float* occ1_w = (const float*)d_in[13];
    const float* occ1_b = (const float*)d_in[14];
    const float* ob_w   = (const float*)d_in[15];
    const float* ob_b   = (const float*)d_in[16];
    const float* occ2_w = (const float*)d_in[17];
    const float* occ2_b = (const float*)d_in[18];
    const float* oc_w   = (const float*)d_in[19];
    const float* oc_b   = (const float*)d_in[20];
    const float* g3_w   = (const float*)d_in[21];
    const float* g3_b   = (const float*)d_in[22];
    const float* lin_w  = (const float*)d_in[23];
    const float* lin_b  = (const float*)d_in[24];
    float* out = (float*)d_out;

    float* ws = (float*)d_ws;
    float* y  = ws;                                  // 802816
    float* kk[6];
    for (int j = 0; j < 6; ++j) kk[j] = ws + (size_t)TOTAL * (1 + j);
    float* h1    = ws + (size_t)TOTAL * 7;           // 14,745,600
    float* h2    = h1 + (size_t)B*64*900;            // 3,686,400
    float* mean1 = h2 + (size_t)B*64*225;
    float* rstd1 = mean1 + B*32;
    float* mean2 = rstd1 + B*32;
    float* rstd2 = mean2 + B*32;

    // ---- preamble CNN ----
    conv1_kernel<<<900, 256, 0, stream>>>(x, c1_w, c1_b, h1);
    gn_stats_kernel<<<B*32, 64, 0, stream>>>(h1, 900, mean1, rstd1);
    gn_apply_kernel<<<4096, 256, 0, stream>>>(h1, mean1, rstd1, g1_w, g1_b, 900, B*64*900);
    conv2_kernel<<<dim3(225, 8), 256, 0, stream>>>(h1, c2_w, c2_b, h2);
    gn_stats_kernel<<<B*32, 64, 0, stream>>>(h2, 225, mean2, rstd2);
    gn_apply_kernel<<<2048, 256, 0, stream>>>(h2, mean2, rstd2, g2_w, g2_b, 225, B*64*225);
    conv3_kernel<<<dim3(49, 8), 256, 0, stream>>>(h2, c3_w, c3_b, y);

    // ---- dopri5 fixed-grid, 6 steps ----
    const double hd = 1.0 / 6.0;
    const float  hf = (float)hd;
    for (int s = 0; s < 6; ++s) {
        float t0 = (float)s * hf;

        f_eval_kernel<<<B, 512, 0, stream>>>(y, y, y, y, y, y,
            0.f, 0.f, 0.f, 0.f, 0.f, 0, t0,
            occ1_w, occ1_b, occ2_w, occ2_b, oa_w, oa_b, ob_w, ob_b, oc_w, oc_b, kk[0]);

        f_eval_kernel<<<B, 512, 0, stream>>>(y, kk[0], y, y, y, y,
            (float)(hd*(1.0/5.0)), 0.f, 0.f, 0.f, 0.f, 1, t0 + hf*(1.f/5.f),
            occ1_w, occ1_b, occ2_w, occ2_b, oa_w, oa_b, ob_w, ob_b, oc_w, oc_b, kk[1]);

        f_eval_kernel<<<B, 512, 0, stream>>>(y, kk[0], kk[1], y, y, y,
            (float)(hd*(3.0/40.0)), (float)(hd*(9.0/40.0)), 0.f, 0.f, 0.f, 2,
            t0 + hf*(3.f/10.f),
            occ1_w, occ1_b, occ2_w, occ2_b, oa_w, oa_b, ob_w, ob_b, oc_w, oc_b, kk[2]);

        f_eval_kernel<<<B, 512, 0, stream>>>(y, kk[0], kk[1], kk[2], y, y,
            (float)(hd*(44.0/45.0)), (float)(hd*(-56.0/15.0)), (float)(hd*(32.0/9.0)),
            0.f, 0.f, 3, t0 + hf*(4.f/5.f),
            occ1_w, occ1_b, occ2_w, occ2_b, oa_w, oa_b, ob_w, ob_b, oc_w, oc_b, kk[3]);

        f_eval_kernel<<<B, 512, 0, stream>>>(y, kk[0], kk[1], kk[2], kk[3], y,
            (float)(hd*(19372.0/6561.0)), (float)(hd*(-25360.0/2187.0)),
            (float)(hd*(64448.0/6561.0)), (float)(hd*(-212.0/729.0)), 0.f, 4,
            t0 + hf*(8.f/9.f),
            occ1_w, occ1_b, occ2_w, occ2_b, oa_w, oa_b, ob_w, ob_b, oc_w, oc_b, kk[4]);

        f_eval_kernel<<<B, 512, 0, stream>>>(y, kk[0], kk[1], kk[2], kk[3], kk[4],
            (float)(hd*(9017.0/3168.0)), (float)(hd*(-355.0/33.0)),
            (float)(hd*(46732.0/5247.0)), (float)(hd*(49.0/176.0)),
            (float)(hd*(-5103.0/18656.0)), 5, t0 + hf,
            occ1_w, occ1_b, occ2_w, occ2_b, oa_w, oa_b, ob_w, ob_b, oc_w, oc_b, kk[5]);

        yupdate_kernel<<<TOTAL/1024, 1024, 0, stream>>>(y, kk[0], kk[2], kk[3], kk[4], kk[5],
            (float)(hd*(35.0/384.0)), (float)(hd*(500.0/1113.0)),
            (float)(hd*(125.0/192.0)), (float)(hd*(-2187.0/6784.0)),
            (float)(hd*(11.0/84.0)));
    }

    // ---- head ----
    head_kernel<<<B, 256, 0, stream>>>(y, g3_w, g3_b, lin_w, lin_b, out);
}

// Round 2
// 1152.601 us; speedup vs baseline: 2.6198x; 2.6198x over previous
//
#include <hip/hip_runtime.h>
#include <hip/hip_bf16.h>

// ---------------------------------------------------------------------------
// Sizes
// ---------------------------------------------------------------------------
#define B 256
#define NCH 64
#define NPIX 49
#define NELEM 3136          // 64*49 per image
#define TOTAL (B*NELEM)

typedef __attribute__((ext_vector_type(8))) short bf16x8;   // 8 bf16 in 4 VGPRs
typedef __attribute__((ext_vector_type(4))) float f32x4;

__device__ __forceinline__ unsigned short f2bf(float f) {
    unsigned u = __float_as_uint(f);
    unsigned r = (u + 0x7fffu + ((u >> 16) & 1u)) >> 16;
    return (unsigned short)r;
}
__device__ __forceinline__ unsigned int f2bf2(float lo, float hi) {
    return (unsigned int)f2bf(lo) | ((unsigned int)f2bf(hi) << 16);
}

// ---------------------------------------------------------------------------
// conv1: x[256,3,32,32] -> h1[256,64,30,30], 3x3 s1 p0 (raw)
// ---------------------------------------------------------------------------
__global__ __launch_bounds__(256) void conv1_kernel(
    const float* __restrict__ x, const float* __restrict__ w,
    const float* __restrict__ bias, float* __restrict__ out)
{
    __shared__ float sw[64*27];
    __shared__ float sb[64];
    const int t = threadIdx.x;
    for (int i = t; i < 64*27; i += 256) sw[i] = w[i];
    if (t < 64) sb[t] = bias[t];
    __syncthreads();

    const int pid = blockIdx.x * 256 + t;
    const int b  = pid / 900;
    const int p  = pid % 900;
    const int oy = p / 30, ox = p % 30;

    float xv[27];
    #pragma unroll
    for (int c = 0; c < 3; ++c)
        #pragma unroll
        for (int ky = 0; ky < 3; ++ky)
            #pragma unroll
            for (int kx = 0; kx < 3; ++kx)
                xv[c*9 + ky*3 + kx] = x[((b*3 + c)*32 + oy + ky)*32 + ox + kx];

    for (int oc = 0; oc < 64; ++oc) {
        float acc = sb[oc];
        #pragma unroll
        for (int j = 0; j < 27; ++j) acc = fmaf(sw[oc*27 + j], xv[j], acc);
        out[(b*64 + oc)*900 + p] = acc;
    }
}

// ---------------------------------------------------------------------------
// GN stats / apply (preamble tensors)
// ---------------------------------------------------------------------------
__global__ __launch_bounds__(64) void gn_stats_kernel(
    const float* __restrict__ x, int HW, float* __restrict__ mean,
    float* __restrict__ rstd)
{
    const int bg = blockIdx.x;
    const int lane = threadIdx.x;
    const float* p = x + (size_t)bg * 2 * HW;
    const int N = 2 * HW;
    float s = 0.f, sq = 0.f;
    for (int i = lane; i < N; i += 64) {
        float v = p[i];
        s += v; sq += v*v;
    }
    #pragma unroll
    for (int off = 1; off < 64; off <<= 1) {
        s  += __shfl_xor(s, off);
        sq += __shfl_xor(sq, off);
    }
    if (lane == 0) {
        float m = s / (float)N;
        float var = sq / (float)N - m*m;
        mean[bg] = m;
        rstd[bg] = rsqrtf(var + 1e-5f);
    }
}

__global__ __launch_bounds__(256) void gn_apply_kernel(
    float* __restrict__ x, const float* __restrict__ mean,
    const float* __restrict__ rstd, const float* __restrict__ gw,
    const float* __restrict__ gb, int HW, int total)
{
    const int stride = gridDim.x * 256;
    for (int i = blockIdx.x*256 + threadIdx.x; i < total; i += stride) {
        int c  = (i / HW) & 63;
        int bg = i / (HW * 2);
        float v = x[i];
        v = (v - mean[bg]) * rstd[bg] * gw[c] + gb[c];
        x[i] = fmaxf(v, 0.f);
    }
}

// ---------------------------------------------------------------------------
// conv2: 4x4 s2 p1, XCD-aware swizzled linear grid of 1800 blocks
// ---------------------------------------------------------------------------
__global__ __launch_bounds__(256) void conv2_kernel(
    const float* __restrict__ in, const float* __restrict__ w,
    const float* __restrict__ bias, float* __restrict__ out)
{
    const int lin = blockIdx.x;                 // 0..1799
    const int v   = (lin & 7)*225 + (lin >> 3); // contiguous per-XCD range
    const int window = v >> 3, slice = v & 7;
    const int t = threadIdx.x;
    const int pid = window * 256 + t;           // < 57600
    const int b = pid / 225, p = pid % 225;
    const int oy = p / 15, ox = p % 15;
    const int oc0 = slice * 8;
    const int iy0 = oy*2 - 1, ix0 = ox*2 - 1;

    float acc[8];
    #pragma unroll
    for (int j = 0; j < 8; ++j) acc[j] = 0.f;

    for (int c = 0; c < 64; ++c) {
        const float* ib = in + ((size_t)(b*64 + c))*900;
        const float* wb = w + (size_t)oc0*1024 + c*16;
        #pragma unroll
        for (int ky = 0; ky < 4; ++ky) {
            int iy = iy0 + ky;
            if (iy < 0 || iy >= 30) continue;
            #pragma unroll
            for (int kx = 0; kx < 4; ++kx) {
                int ix = ix0 + kx;
                if (ix < 0 || ix >= 30) continue;
                float vv = ib[iy*30 + ix];
                #pragma unroll
                for (int j = 0; j < 8; ++j)
                    acc[j] = fmaf(vv, wb[j*1024 + ky*4 + kx], acc[j]);
            }
        }
    }
    #pragma unroll
    for (int j = 0; j < 8; ++j)
        out[((size_t)(b*64 + oc0 + j))*225 + p] = acc[j] + bias[oc0 + j];
}

// ---------------------------------------------------------------------------
// conv3: 4x4 s2 p1 -> y[256,64,7,7], swizzled 392 blocks
// ---------------------------------------------------------------------------
__global__ __launch_bounds__(256) void conv3_kernel(
    const float* __restrict__ in, const float* __restrict__ w,
    const float* __restrict__ bias, float* __restrict__ out)
{
    const int lin = blockIdx.x;                 // 0..391
    const int v   = (lin & 7)*49 + (lin >> 3);
    const int window = v >> 3, slice = v & 7;
    const int t = threadIdx.x;
    const int pid = window * 256 + t;           // < 12544
    const int b = pid / 49, p = pid % 49;
    const int oy = p / 7, ox = p % 7;
    const int oc0 = slice * 8;
    const int iy0 = oy*2 - 1, ix0 = ox*2 - 1;

    float acc[8];
    #pragma unroll
    for (int j = 0; j < 8; ++j) acc[j] = 0.f;

    for (int c = 0; c < 64; ++c) {
        const float* ib = in + ((size_t)(b*64 + c))*225;
        const float* wb = w + (size_t)oc0*1024 + c*16;
        #pragma unroll
        for (int ky = 0; ky < 4; ++ky) {
            int iy = iy0 + ky;
            if (iy < 0 || iy >= 15) continue;
            #pragma unroll
            for (int kx = 0; kx < 4; ++kx) {
                int ix = ix0 + kx;
                if (ix < 0 || ix >= 15) continue;
                float vv = ib[iy*15 + ix];
                #pragma unroll
                for (int j = 0; j < 8; ++j)
                    acc[j] = fmaf(vv, wb[j*1024 + ky*4 + kx], acc[j]);
            }
        }
    }
    #pragma unroll
    for (int j = 0; j < 8; ++j)
        out[((size_t)(b*64 + oc0 + j))*49 + p] = acc[j] + bias[oc0 + j];
}

// ---------------------------------------------------------------------------
// Prep: weight fragments for MFMA (k = tap*64 + ic, ic = model channel-1)
// A[m][k] elem: lane l holds rows l&15, k-chunk (l>>4)*8 + j
// af layout: [(mt*18+kt)*64 + lane]*8 + j
// ---------------------------------------------------------------------------
__global__ __launch_bounds__(256) void prep_afrag_kernel(
    const float* __restrict__ w1, const float* __restrict__ w2,
    short* __restrict__ af1, short* __restrict__ af2)
{
    const int e = blockIdx.x * 256 + threadIdx.x;   // < 36864
    const float* W = blockIdx.y ? w2 : w1;
    short* dst = blockIdx.y ? af2 : af1;
    const int j = e & 7;
    const int lane = (e >> 3) & 63;
    const int kt = (e >> 9) % 18;
    const int mt = (e >> 9) / 18;
    const int m = mt*16 + (lane & 15);
    const int k = kt*32 + ((lane >> 4) & 3)*8 + j;
    const int tap = k >> 6;          // k = tap*64 + ic
    const int ic  = k & 63;
    const float val = W[m*585 + (ic + 1)*9 + tap];
    dst[e] = (short)f2bf(val);
}

// stab[oc*49+p] = sum of t-channel weights over taps valid at pixel p
__global__ __launch_bounds__(256) void prep_stab_kernel(
    const float* __restrict__ w1, const float* __restrict__ w2,
    float* __restrict__ stab1, float* __restrict__ stab2)
{
    const int id = blockIdx.x * 256 + threadIdx.x;
    if (id >= 3136) return;
    const float* W = blockIdx.y ? w2 : w1;
    float* dst = blockIdx.y ? stab2 : stab1;
    const int oc = id / 49, p = id % 49;
    const int py = p / 7, px = p % 7;
    float s = 0.f;
    #pragma unroll
    for (int ky = 0; ky < 3; ++ky) {
        int iy = py - 1 + ky;
        if (iy < 0 || iy > 6) continue;
        #pragma unroll
        for (int kx = 0; kx < 3; ++kx) {
            int ix = px - 1 + kx;
            if (ix < 0 || ix > 6) continue;
            s += W[oc*585 + ky*3 + kx];   // ic_model = 0 (t channel)
        }
    }
    dst[id] = s;
}

// ---------------------------------------------------------------------------
// In-register GroupNorm stats: each wave holds D-tiles (mt, ntA/ntB)
// ---------------------------------------------------------------------------
__device__ __forceinline__ void gn_inreg(
    const float v0[4], const float v1[4], bool vA, bool vB,
    int w, int lhi, int llo, int t,
    float* gnred, float* s_mean, float* s_rstd)
{
    float s0 = 0.f, q0 = 0.f, s1 = 0.f, q1 = 0.f;
    if (vA) {
        s0 += v0[0] + v0[1]; q0 += v0[0]*v0[0] + v0[1]*v0[1];
        s1 += v0[2] + v0[3]; q1 += v0[2]*v0[2] + v0[3]*v0[3];
    }
    if (vB) {
        s0 += v1[0] + v1[1]; q0 += v1[0]*v1[0] + v1[1]*v1[1];
        s1 += v1[2] + v1[3]; q1 += v1[2]*v1[2] + v1[3]*v1[3];
    }
    #pragma unroll
    for (int off = 1; off < 16; off <<= 1) {
        s0 += __shfl_xor(s0, off); q0 += __shfl_xor(q0, off);
        s1 += __shfl_xor(s1, off); q1 += __shfl_xor(q1, off);
    }
    if (llo == 0) {
        float* gp = gnred + w*16 + lhi*4;
        gp[0] = s0; gp[1] = q0; gp[2] = s1; gp[3] = q1;
    }
    __syncthreads();
    if (t < 32) {
        const int mtg = t >> 3, qq = (t >> 1) & 3, hh = t & 1;
        const int i0 = (mtg*2)*16 + qq*4 + hh*2;
        const int i1 = i0 + 16;
        float s  = gnred[i0]   + gnred[i1];
        float q  = gnred[i0+1] + gnred[i1+1];
        float m  = s * (1.f/98.f);
        float var = q * (1.f/98.f) - m*m;
        s_mean[t] = m;
        s_rstd[t] = rsqrtf(var + 1e-5f);
    }
    __syncthreads();
}

// ---------------------------------------------------------------------------
// Full f evaluation, MFMA version. One block (512 thr, 8 waves) per image.
// LDS act: [81 padded pixels][72 ch] bf16, ping-pong x2.
// ---------------------------------------------------------------------------
__global__ __launch_bounds__(512, 2) void f_eval_mfma(
    const float* __restrict__ ybase,
    const float* __restrict__ kA, const float* __restrict__ kB,
    const float* __restrict__ kC, const float* __restrict__ kD,
    const float* __restrict__ kE,
    float cA, float cB, float cC, float cD, float cE, int nk, float tval,
    const short* __restrict__ af1, const short* __restrict__ af2,
    const float* __restrict__ stab1, const float* __restrict__ stab2,
    const float* __restrict__ b1v, const float* __restrict__ b2v,
    const float* __restrict__ oaw, const float* __restrict__ oab,
    const float* __restrict__ obw, const float* __restrict__ obb,
    const float* __restrict__ ocw, const float* __restrict__ ocb,
    float* __restrict__ kout)
{
    __shared__ short act[2][5832];      // [81][72] x2
    __shared__ float scr[3136];
    __shared__ float gnred[128];
    __shared__ float s_mean[32], s_rstd[32];

    const int t = threadIdx.x;
    const int b = blockIdx.x;
    const int boff = b * NELEM;
    const int w = t >> 6, l = t & 63, lhi = l >> 4, llo = l & 15;
    const int mt = w >> 1;
    const int ntA = (w & 1) * 2, ntB = ntA + 1;
    const int nA = ntA*16 + llo, nB = ntB*16 + llo;
    const bool vA = nA < 49, vB = nB < 49;
    const int nsA = vA ? nA : 48, nsB = vB ? nB : 48;
    const int ctrA = (nsA/7 + 1)*9 + (nsA%7 + 1);
    const int ctrB = (nsB/7 + 1)*9 + (nsB%7 + 1);
    const int oc0 = mt*16 + lhi*4;

    // zero act buffers (borders must be 0; interior rewritten below)
    {
        unsigned int* az = (unsigned int*)act;
        for (int i = t; i < 5832; i += 512) az[i] = 0u;
    }
    // stage combine -> scr (fp32)
    for (int i = t; i < NELEM; i += 512) {
        float v = ybase[boff + i];
        if (nk > 0) v = fmaf(cA, kA[boff + i], v);
        if (nk > 1) v = fmaf(cB, kB[boff + i], v);
        if (nk > 2) v = fmaf(cC, kC[boff + i], v);
        if (nk > 3) v = fmaf(cD, kD[boff + i], v);
        if (nk > 4) v = fmaf(cE, kE[boff + i], v);
        scr[i] = v;
    }
    __syncthreads();

    // GN_oa stats: 32 groups x 16 threads over contiguous 98-elem groups
    {
        const int g = t >> 4, sub = t & 15;
        float s = 0.f, q = 0.f;
        for (int e = sub; e < 98; e += 16) {
            float v = scr[g*98 + e];
            s += v; q += v*v;
        }
        s += __shfl_xor(s, 1); q += __shfl_xor(q, 1);
        s += __shfl_xor(s, 2); q += __shfl_xor(q, 2);
        s += __shfl_xor(s, 4); q += __shfl_xor(q, 4);
        s += __shfl_xor(s, 8); q += __shfl_xor(q, 8);
        if (sub == 0) {
            float m = s * (1.f/98.f);
            float var = q * (1.f/98.f) - m*m;
            s_mean[g] = m;
            s_rstd[g] = rsqrtf(var + 1e-5f);
        }
    }
    __syncthreads();

    // normalize + relu -> act[0], packed channel pairs
    for (int idx = t; idx < 1568; idx += 512) {
        const int p = idx >> 5, c = idx & 31;
        const int ch = c * 2;
        const float m = s_mean[c], r = s_rstd[c];
        float x0 = fmaxf((scr[ch*49 + p]       - m)*r*oaw[ch]   + oab[ch],   0.f);
        float x1 = fmaxf((scr[(ch+1)*49 + p]   - m)*r*oaw[ch+1] + oab[ch+1], 0.f);
        const int pa = (p/7 + 1)*9 + (p%7 + 1);
        *(unsigned int*)&act[0][pa*72 + ch] = f2bf2(x0, x1);
    }

    // A1 strip load (global, L2-resident)
    bf16x8 aw1[18];
    #pragma unroll
    for (int kt = 0; kt < 18; ++kt)
        aw1[kt] = *(const bf16x8*)(af1 + ((size_t)(mt*18 + kt)*64 + l)*8);
    __syncthreads();

    // ---- conv1 MFMA ----
    f32x4 acc0 = {0.f,0.f,0.f,0.f}, acc1 = {0.f,0.f,0.f,0.f};
    #pragma unroll
    for (int kt = 0; kt < 18; ++kt) {
        const int tap = kt >> 1;
        const int toff = (tap/3 - 1)*9 + (tap%3 - 1);
        const int ico = (kt & 1)*32 + lhi*8;
        bf16x8 bb0 = *(const bf16x8*)&act[0][(ctrA + toff)*72 + ico];
        bf16x8 bb1 = *(const bf16x8*)&act[0][(ctrB + toff)*72 + ico];
        acc0 = __builtin_amdgcn_mfma_f32_16x16x32_bf16(aw1[kt], bb0, acc0, 0, 0, 0);
        acc1 = __builtin_amdgcn_mfma_f32_16x16x32_bf16(aw1[kt], bb1, acc1, 0, 0, 0);
    }

    // prefetch A2 strip while GN runs
    bf16x8 aw2[18];
    #pragma unroll
    for (int kt = 0; kt < 18; ++kt)
        aw2[kt] = *(const bf16x8*)(af2 + ((size_t)(mt*18 + kt)*64 + l)*8);

    // epilogue 1: bias + t * S(t-channel)
    float v0[4], v1[4];
    {
        f32x4 bia = *(const f32x4*)&b1v[oc0];
        #pragma unroll
        for (int r = 0; r < 4; ++r) {
            v0[r] = acc0[r] + bia[r] + tval * stab1[(oc0 + r)*49 + nsA];
            v1[r] = acc1[r] + bia[r] + tval * stab1[(oc0 + r)*49 + nsB];
        }
    }

    // GN_ob (stats in registers)
    gn_inreg(v0, v1, vA, vB, w, lhi, llo, t, gnred, s_mean, s_rstd);
    {
        f32x4 gww = *(const f32x4*)&obw[oc0];
        f32x4 gbb = *(const f32x4*)&obb[oc0];
        const int g0 = oc0 >> 1;
        const float m0 = s_mean[g0],   r0 = s_rstd[g0];
        const float m1 = s_mean[g0+1], r1 = s_rstd[g0+1];
        v0[0] = fmaxf((v0[0]-m0)*r0*gww[0]+gbb[0], 0.f);
        v0[1] = fmaxf((v0[1]-m0)*r0*gww[1]+gbb[1], 0.f);
        v0[2] = fmaxf((v0[2]-m1)*r1*gww[2]+gbb[2], 0.f);
        v0[3] = fmaxf((v0[3]-m1)*r1*gww[3]+gbb[3], 0.f);
        v1[0] = fmaxf((v1[0]-m0)*r0*gww[0]+gbb[0], 0.f);
        v1[1] = fmaxf((v1[1]-m0)*r0*gww[1]+gbb[1], 0.f);
        v1[2] = fmaxf((v1[2]-m1)*r1*gww[2]+gbb[2], 0.f);
        v1[3] = fmaxf((v1[3]-m1)*r1*gww[3]+gbb[3], 0.f);
        if (vA) {
            unsigned int* dA = (unsigned int*)&act[1][ctrA*72 + oc0];
            dA[0] = f2bf2(v0[0], v0[1]);
            dA[1] = f2bf2(v0[2], v0[3]);
        }
        if (vB) {
            unsigned int* dB = (unsigned int*)&act[1][ctrB*72 + oc0];
            dB[0] = f2bf2(v1[0], v1[1]);
            dB[1] = f2bf2(v1[2], v1[3]);
        }
    }
    __syncthreads();

    // ---- conv2 MFMA ----
    acc0 = (f32x4){0.f,0.f,0.f,0.f};
    acc1 = (f32x4){0.f,0.f,0.f,0.f};
    #pragma unroll
    for (int kt = 0; kt < 18; ++kt) {
        const int tap = kt >> 1;
        const int toff = (tap/3 - 1)*9 + (tap%3 - 1);
        const int ico = (kt & 1)*32 + lhi*8;
        bf16x8 bb0 = *(const bf16x8*)&act[1][(ctrA + toff)*72 + ico];
        bf16x8 bb1 = *(const bf16x8*)&act[1][(ctrB + toff)*72 + ico];
        acc0 = __builtin_amdgcn_mfma_f32_16x16x32_bf16(aw2[kt], bb0, acc0, 0, 0, 0);
        acc1 = __builtin_amdgcn_mfma_f32_16x16x32_bf16(aw2[kt], bb1, acc1, 0, 0, 0);
    }

    // epilogue 2
    {
        f32x4 bia = *(const f32x4*)&b2v[oc0];
        #pragma unroll
        for (int r = 0; r < 4; ++r) {
            v0[r] = acc0[r] + bia[r] + tval * stab2[(oc0 + r)*49 + nsA];
            v1[r] = acc1[r] + bia[r] + tval * stab2[(oc0 + r)*49 + nsB];
        }
    }

    // GN_oc (no relu) -> kout
    gn_inreg(v0, v1, vA, vB, w, lhi, llo, t, gnred, s_mean, s_rstd);
    {
        f32x4 gww = *(const f32x4*)&ocw[oc0];
        f32x4 gbb = *(const f32x4*)&ocb[oc0];
        const int g0 = oc0 >> 1;
        const float m0 = s_mean[g0],   r0 = s_rstd[g0];
        const float m1 = s_mean[g0+1], r1 = s_rstd[g0+1];
        if (vA) {
            kout[boff + (oc0+0)*49 + nA] = (v0[0]-m0)*r0*gww[0]+gbb[0];
            kout[boff + (oc0+1)*49 + nA] = (v0[1]-m0)*r0*gww[1]+gbb[1];
            kout[boff + (oc0+2)*49 + nA] = (v0[2]-m1)*r1*gww[2]+gbb[2];
            kout[boff + (oc0+3)*49 + nA] = (v0[3]-m1)*r1*gww[3]+gbb[3];
        }
        if (vB) {
            kout[boff + (oc0+0)*49 + nB] = (v1[0]-m0)*r0*gww[0]+gbb[0];
            kout[boff + (oc0+1)*49 + nB] = (v1[1]-m0)*r0*gww[1]+gbb[1];
            kout[boff + (oc0+2)*49 + nB] = (v1[2]-m1)*r1*gww[2]+gbb[2];
            kout[boff + (oc0+3)*49 + nB] = (v1[3]-m1)*r1*gww[3]+gbb[3];
        }
    }
}

// ---------------------------------------------------------------------------
// y += b1*k1 + b3*k3 + b4*k4 + b5*k5 + b6*k6   (coeffs include h)
// ---------------------------------------------------------------------------
__global__ __launch_bounds__(1024) void yupdate_kernel(
    float* __restrict__ y,
    const float* __restrict__ k1, const float* __restrict__ k3,
    const float* __restrict__ k4, const float* __restrict__ k5,
    const float* __restrict__ k6,
    float b1, float b3, float b4, float b5, float b6)
{
    int i = blockIdx.x * 1024 + threadIdx.x;
    float v = y[i];
    v = fmaf(b1, k1[i], v);
    v = fmaf(b3, k3[i], v);
    v = fmaf(b4, k4[i], v);
    v = fmaf(b5, k5[i], v);
    v = fmaf(b6, k6[i], v);
    y[i] = v;
}

// ---------------------------------------------------------------------------
// head: GN(g3)+ReLU -> spatial mean -> linear [64 -> 10]
// ---------------------------------------------------------------------------
__global__ __launch_bounds__(256) void head_kernel(
    const float* __restrict__ y,
    const float* __restrict__ g3_w, const float* __restrict__ g3_b,
    const float* __restrict__ lin_w, const float* __restrict__ lin_b,
    float* __restrict__ out)
{
    __shared__ float s_y[NELEM];
    __shared__ float s_mean[32], s_rstd[32];
    __shared__ float s_cm[64];
    const int t = threadIdx.x, b = blockIdx.x;

    for (int i = t; i < NELEM; i += 256) s_y[i] = y[b*NELEM + i];
    __syncthreads();

    {
        const int g = t >> 3, sub = t & 7;
        float s = 0.f, sq = 0.f;
        for (int e = sub; e < 98; e += 8) {
            float v = s_y[g*98 + e];
            s += v; sq += v*v;
        }
        s += __shfl_xor(s, 1);  sq += __shfl_xor(sq, 1);
        s += __shfl_xor(s, 2);  sq += __shfl_xor(sq, 2);
        s += __shfl_xor(s, 4);  sq += __shfl_xor(sq, 4);
        if (sub == 0) {
            float m = s * (1.f/98.f);
            float var = sq * (1.f/98.f) - m*m;
            s_mean[g] = m;
            s_rstd[g] = rsqrtf(var + 1e-5f);
        }
    }
    __syncthreads();

    if (t < 64) {
        const int ch = t, g = ch >> 1;
        float m = s_mean[g], r = s_rstd[g];
        float w = g3_w[ch], bb = g3_b[ch];
        float sum = 0.f;
        for (int p = 0; p < 49; ++p) {
            float v = (s_y[ch*49 + p] - m) * r * w + bb;
            sum += fmaxf(v, 0.f);
        }
        s_cm[ch] = sum * (1.f/49.f);
    }
    __syncthreads();

    if (t < 10) {
        float a = lin_b[t];
        for (int c = 0; c < 64; ++c) a = fmaf(s_cm[c], lin_w[t*64 + c], a);
        out[b*10 + t] = a;
    }
}

// ---------------------------------------------------------------------------
// Host launch
// ---------------------------------------------------------------------------
extern "C" void kernel_launch(void* const* d_in, const int* in_sizes, int n_in,
                              void* d_out, int out_size, void* d_ws, size_t ws_size,
                              hipStream_t stream)
{
    const float* x      = (const float*)d_in[0];
    const float* c1_w   = (const float*)d_in[1];
    const float* c1_b   = (const float*)d_in[2];
    const float* g1_w   = (const float*)d_in[3];
    const float* g1_b   = (const float*)d_in[4];
    const float* c2_w   = (const float*)d_in[5];
    const float* c2_b   = (const float*)d_in[6];
    const float* g2_w   = (const float*)d_in[7];
    const float* g2_b   = (const float*)d_in[8];
    const float* c3_w   = (const float*)d_in[9];
    const float* c3_b   = (const float*)d_in[10];
    const float* oa_w   = (const float*)d_in[11];
    const float* oa_b   = (const float*)d_in[12];
    const float* occ1_w = (const float*)d_in[13];
    const float* occ1_b = (const float*)d_in[14];
    const float* ob_w   = (const float*)d_in[15];
    const float* ob_b   = (const float*)d_in[16];
    const float* occ2_w = (const float*)d_in[17];
    const float* occ2_b = (const float*)d_in[18];
    const float* oc_w   = (const float*)d_in[19];
    const float* oc_b   = (const float*)d_in[20];
    const float* g3_w   = (const float*)d_in[21];
    const float* g3_b   = (const float*)d_in[22];
    const float* lin_w  = (const float*)d_in[23];
    const float* lin_b  = (const float*)d_in[24];
    float* out = (float*)d_out;

    float* ws = (float*)d_ws;
    float* y     = ws;                                  // 802816
    float* h1    = ws + (size_t)TOTAL;                  // 14745600 (kk overlaps)
    float* kk[6];
    for (int j = 0; j < 6; ++j) kk[j] = h1 + (size_t)TOTAL * j;   // ODE phase only
    float* h2    = h1 + (size_t)B*64*900;
    float* mean1 = h2 + (size_t)B*64*225;
    float* rstd1 = mean1 + B*32;
    float* mean2 = rstd1 + B*32;
    float* rstd2 = mean2 + B*32;
    float* stab1 = rstd2 + B*32;                        // 3136
    float* stab2 = stab1 + 3136;                        // 3136
    short* af1   = (short*)(stab2 + 3136);              // 36864 shorts
    short* af2   = af1 + 36864;

    // ---- prep (weights constant per launch) ----
    prep_afrag_kernel<<<dim3(144, 2), 256, 0, stream>>>(occ1_w, occ2_w, af1, af2);
    prep_stab_kernel<<<dim3(13, 2), 256, 0, stream>>>(occ1_w, occ2_w, stab1, stab2);

    // ---- preamble CNN ----
    conv1_kernel<<<900, 256, 0, stream>>>(x, c1_w, c1_b, h1);
    gn_stats_kernel<<<B*32, 64, 0, stream>>>(h1, 900, mean1, rstd1);
    gn_apply_kernel<<<4096, 256, 0, stream>>>(h1, mean1, rstd1, g1_w, g1_b, 900, B*64*900);
    conv2_kernel<<<1800, 256, 0, stream>>>(h1, c2_w, c2_b, h2);
    gn_stats_kernel<<<B*32, 64, 0, stream>>>(h2, 225, mean2, rstd2);
    gn_apply_kernel<<<2048, 256, 0, stream>>>(h2, mean2, rstd2, g2_w, g2_b, 225, B*64*225);
    conv3_kernel<<<392, 256, 0, stream>>>(h2, c3_w, c3_b, y);

    // ---- dopri5 fixed-grid, 6 steps ----
    const double hd = 1.0 / 6.0;
    const float  hf = (float)hd;
    for (int s = 0; s < 6; ++s) {
        float t0 = (float)s * hf;

        f_eval_mfma<<<B, 512, 0, stream>>>(y, y, y, y, y, y,
            0.f, 0.f, 0.f, 0.f, 0.f, 0, t0,
            af1, af2, stab1, stab2, occ1_b, occ2_b,
            oa_w, oa_b, ob_w, ob_b, oc_w, oc_b, kk[0]);

        f_eval_mfma<<<B, 512, 0, stream>>>(y, kk[0], y, y, y, y,
            (float)(hd*(1.0/5.0)), 0.f, 0.f, 0.f, 0.f, 1, t0 + hf*(1.f/5.f),
            af1, af2, stab1, stab2, occ1_b, occ2_b,
            oa_w, oa_b, ob_w, ob_b, oc_w, oc_b, kk[1]);

        f_eval_mfma<<<B, 512, 0, stream>>>(y, kk[0], kk[1], y, y, y,
            (float)(hd*(3.0/40.0)), (float)(hd*(9.0/40.0)), 0.f, 0.f, 0.f, 2,
            t0 + hf*(3.f/10.f),
            af1, af2, stab1, stab2, occ1_b, occ2_b,
            oa_w, oa_b, ob_w, ob_b, oc_w, oc_b, kk[2]);

        f_eval_mfma<<<B, 512, 0, stream>>>(y, kk[0], kk[1], kk[2], y, y,
            (float)(hd*(44.0/45.0)), (float)(hd*(-56.0/15.0)), (float)(hd*(32.0/9.0)),
            0.f, 0.f, 3, t0 + hf*(4.f/5.f),
            af1, af2, stab1, stab2, occ1_b, occ2_b,
            oa_w, oa_b, ob_w, ob_b, oc_w, oc_b, kk[3]);

        f_eval_mfma<<<B, 512, 0, stream>>>(y, kk[0], kk[1], kk[2], kk[3], y,
            (float)(hd*(19372.0/6561.0)), (float)(hd*(-25360.0/2187.0)),
            (float)(hd*(64448.0/6561.0)), (float)(hd*(-212.0/729.0)), 0.f, 4,
            t0 + hf*(8.f/9.f),
            af1, af2, stab1, stab2, occ1_b, occ2_b,
            oa_w, oa_b, ob_w, ob_b, oc_w, oc_b, kk[4]);

        f_eval_mfma<<<B, 512, 0, stream>>>(y, kk[0], kk[1], kk[2], kk[3], kk[4],
            (float)(hd*(9017.0/3168.0)), (float)(hd*(-355.0/33.0)),
            (float)(hd*(46732.0/5247.0)), (float)(hd*(49.0/176.0)),
            (float)(hd*(-5103.0/18656.0)), 5, t0 + hf,
            af1, af2, stab1, stab2, occ1_b, occ2_b,
            oa_w, oa_b, ob_w, ob_b, oc_w, oc_b, kk[5]);

        yupdate_kernel<<<TOTAL/1024, 1024, 0, stream>>>(y, kk[0], kk[2], kk[3], kk[4], kk[5],
            (float)(hd*(35.0/384.0)), (float)(hd*(500.0/1113.0)),
            (float)(hd*(125.0/192.0)), (float)(hd*(-2187.0/6784.0)),
            (float)(hd*(11.0/84.0)));
    }

    // ---- head ----
    head_kernel<<<B, 256, 0, stream>>>(y, g3_w, g3_b, lin_w, lin_b, out);
}

// Round 3
// 411.739 us; speedup vs baseline: 7.3337x; 2.7994x over previous
//
#include <hip/hip_runtime.h>
#include <hip/hip_bf16.h>

#define B 256
#define NELEM 3136          // 64*49 per image
#define TOTAL (B*NELEM)

typedef __attribute__((ext_vector_type(8))) short bf16x8;
typedef __attribute__((ext_vector_type(4))) float f32x4;

__device__ __forceinline__ unsigned short f2bf(float f) {
    unsigned u = __float_as_uint(f);
    unsigned r = (u + 0x7fffu + ((u >> 16) & 1u)) >> 16;
    return (unsigned short)r;
}
__device__ __forceinline__ unsigned int f2bf2(float lo, float hi) {
    return (unsigned int)f2bf(lo) | ((unsigned int)f2bf(hi) << 16);
}

// ---------------------------------------------------------------------------
// Weight-fragment prep kernels
// ---------------------------------------------------------------------------
// ODE convs (65ch incl t -> handled via stab; K = tap*64+ic over 64 real ch)
__global__ __launch_bounds__(256) void prep_afrag_kernel(
    const float* __restrict__ w1, const float* __restrict__ w2,
    short* __restrict__ af1, short* __restrict__ af2)
{
    const int e = blockIdx.x * 256 + threadIdx.x;   // < 36864
    const float* W = blockIdx.y ? w2 : w1;
    short* dst = blockIdx.y ? af2 : af1;
    const int j = e & 7;
    const int lane = (e >> 3) & 63;
    const int kt = (e >> 9) % 18;
    const int mt = (e >> 9) / 18;
    const int m = mt*16 + (lane & 15);
    const int k = kt*32 + ((lane >> 4) & 3)*8 + j;
    const int tap = k >> 6;
    const int ic  = k & 63;
    dst[e] = (short)f2bf(W[m*585 + (ic + 1)*9 + tap]);
}

// stab[oc*49+p] = sum of t-channel weights over taps valid at pixel p
__global__ __launch_bounds__(256) void prep_stab_kernel(
    const float* __restrict__ w1, const float* __restrict__ w2,
    float* __restrict__ stab1, float* __restrict__ stab2)
{
    const int id = blockIdx.x * 256 + threadIdx.x;
    if (id >= 3136) return;
    const float* W = blockIdx.y ? w2 : w1;
    float* dst = blockIdx.y ? stab2 : stab1;
    const int oc = id / 49, p = id % 49;
    const int py = p / 7, px = p % 7;
    float s = 0.f;
    #pragma unroll
    for (int ky = 0; ky < 3; ++ky) {
        int iy = py - 1 + ky;
        if (iy < 0 || iy > 6) continue;
        #pragma unroll
        for (int kx = 0; kx < 3; ++kx) {
            int ix = px - 1 + kx;
            if (ix < 0 || ix > 6) continue;
            s += W[oc*585 + ky*3 + kx];
        }
    }
    dst[id] = s;
}

// conv1 weights: K=32 (27 real taps: k = c*9 + ky*3 + kx, pad 0)
__global__ __launch_bounds__(256) void prep_c1frag_kernel(
    const float* __restrict__ w1, short* __restrict__ afc1)
{
    const int e = blockIdx.x * 256 + threadIdx.x;   // < 2048
    const int j = e & 7, lane = (e >> 3) & 63, mtq = e >> 9;
    const int m = mtq*16 + (lane & 15);
    const int k = ((lane >> 4) & 3)*8 + j;
    float v = (k < 27) ? w1[m*27 + k] : 0.f;
    afc1[e] = (short)f2bf(v);
}

// conv2/conv3 weights: K = tap*64 + ic (taps 4x4 = ky*4+kx)
__global__ __launch_bounds__(256) void prep_c23frag_kernel(
    const float* __restrict__ w2, const float* __restrict__ w3,
    short* __restrict__ afc2, short* __restrict__ afc3)
{
    const int e = blockIdx.x * 256 + threadIdx.x;   // < 65536
    const float* W = blockIdx.y ? w3 : w2;
    short* dst = blockIdx.y ? afc3 : afc2;
    const int j = e & 7, lane = (e >> 3) & 63, kt = (e >> 9) & 31, mtq = e >> 14;
    const int m = mtq*16 + (lane & 15);
    const int k = kt*32 + ((lane >> 4) & 3)*8 + j;
    const int tap = k >> 6, ic = k & 63;
    dst[e] = (short)f2bf(W[m*1024 + ic*16 + tap]);
}

// ---------------------------------------------------------------------------
// conv1 + GN1 + ReLU fused, MFMA. One block per image.
// Output: h1pad bf16 [32x32 padded pixels][64 ch], XOR-slot-swizzled.
// ---------------------------------------------------------------------------
__global__ __launch_bounds__(512, 1) void conv1_fused(
    const float* __restrict__ x, const short* __restrict__ afc1,
    const float* __restrict__ bias,
    const float* __restrict__ g1w, const float* __restrict__ g1b,
    short* __restrict__ h1pad)
{
    __shared__ float xs[3072];
    __shared__ float gnred[128], gnq[128];
    __shared__ float s_mean[32], s_rstd[32];

    const int t = threadIdx.x, b = blockIdx.x;
    const int w = t >> 6, l = t & 63, lhi = (l >> 4) & 3, llo = l & 15;
    const int mt = w & 3, sub = w >> 2;
    const int oc0 = mt*16 + lhi*4;

    for (int i = t; i < 3072; i += 512) xs[i] = x[b*3072 + i];

    bf16x8 afr = *(const bf16x8*)(afc1 + ((size_t)(mt*64 + l))*8);

    int boff[8]; bool bval[8];
    #pragma unroll
    for (int j = 0; j < 8; ++j) {
        int k = lhi*8 + j;
        bval[j] = (k < 27);
        int kk = bval[j] ? k : 0;
        int c = kk / 9, tap = kk % 9;
        boff[j] = c*1024 + (tap/3)*32 + (tap%3);
    }
    f32x4 bia = *(const f32x4*)&bias[oc0];
    __syncthreads();

    f32x4 acc[29];
    float s[4] = {0,0,0,0}, q[4] = {0,0,0,0};
    #pragma unroll
    for (int i = 0; i < 29; ++i) {
        const int nt = sub*29 + i;
        f32x4 a = {0.f,0.f,0.f,0.f};
        if (nt < 57) {
            const int p = nt*16 + llo;
            const int pc = p < 900 ? p : 899;
            const int base = (pc/30)*32 + (pc%30);
            union { bf16x8 v; unsigned u[4]; } bb;
            #pragma unroll
            for (int jj = 0; jj < 4; ++jj) {
                float e0 = bval[2*jj]   ? xs[boff[2*jj]   + base] : 0.f;
                float e1 = bval[2*jj+1] ? xs[boff[2*jj+1] + base] : 0.f;
                bb.u[jj] = f2bf2(e0, e1);
            }
            a = __builtin_amdgcn_mfma_f32_16x16x32_bf16(afr, bb.v, a, 0, 0, 0);
            #pragma unroll
            for (int r = 0; r < 4; ++r) {
                a[r] += bia[r];
                if (p < 900) { s[r] += a[r]; q[r] += a[r]*a[r]; }
            }
        }
        acc[i] = a;
    }

    #pragma unroll
    for (int off = 1; off < 16; off <<= 1) {
        #pragma unroll
        for (int r = 0; r < 4; ++r) {
            s[r] += __shfl_xor(s[r], off);
            q[r] += __shfl_xor(q[r], off);
        }
    }
    if (llo == 0) {
        #pragma unroll
        for (int r = 0; r < 4; ++r) {
            gnred[w*16 + lhi*4 + r] = s[r];
            gnq[w*16 + lhi*4 + r]   = q[r];
        }
    }
    __syncthreads();
    if (t < 32) {
        const int oc = t*2;
        const int mtg = oc >> 4, lh = (oc >> 2) & 3, r0 = oc & 3;
        const int i0 = mtg*16 + lh*4 + r0;
        float ss = gnred[i0] + gnred[i0+1] + gnred[i0+64] + gnred[i0+65];
        float qq = gnq[i0]   + gnq[i0+1]   + gnq[i0+64]   + gnq[i0+65];
        float m = ss * (1.f/1800.f);
        float var = qq * (1.f/1800.f) - m*m;
        s_mean[t] = m; s_rstd[t] = rsqrtf(var + 1e-5f);
    }
    __syncthreads();

    const int g0 = oc0 >> 1;
    const float m0 = s_mean[g0],   rs0 = s_rstd[g0];
    const float m1 = s_mean[g0+1], rs1 = s_rstd[g0+1];
    const float w0 = g1w[oc0], w1v = g1w[oc0+1], w2v = g1w[oc0+2], w3v = g1w[oc0+3];
    const float b0 = g1b[oc0], b1v_ = g1b[oc0+1], b2v_ = g1b[oc0+2], b3v_ = g1b[oc0+3];
    char* hb = (char*)h1pad + (size_t)b*131072;

    #pragma unroll
    for (int i = 0; i < 29; ++i) {
        const int nt = sub*29 + i;
        if (nt >= 57) continue;
        const int p = nt*16 + llo;
        if (p >= 900) continue;
        const int pidx = (p/30 + 1)*32 + (p%30 + 1);
        float v0 = fmaxf((acc[i][0]-m0)*rs0*w0  + b0,   0.f);
        float v1 = fmaxf((acc[i][1]-m0)*rs0*w1v + b1v_, 0.f);
        float v2 = fmaxf((acc[i][2]-m1)*rs1*w2v + b2v_, 0.f);
        float v3 = fmaxf((acc[i][3]-m1)*rs1*w3v + b3v_, 0.f);
        uint2 pk; pk.x = f2bf2(v0, v1); pk.y = f2bf2(v2, v3);
        int byte = (pidx*128 + oc0*2) ^ (((pidx>>1)&7) << 4);
        *(uint2*)(hb + byte) = pk;
    }
    // zero the 124 border pixels (full 128B rows; XOR immaterial)
    for (int u = t; u < 124*8; u += 512) {
        const int bp = u >> 3, slot = u & 7;
        int pidx;
        if (bp < 32) pidx = bp;
        else if (bp < 64) pidx = 31*32 + (bp - 32);
        else if (bp < 94) pidx = (bp - 64 + 1)*32;
        else pidx = (bp - 94 + 1)*32 + 31;
        uint4 z; z.x = z.y = z.z = z.w = 0u;
        *(uint4*)(hb + pidx*128 + slot*16) = z;
    }
}

// ---------------------------------------------------------------------------
// conv2 + GN2 + ReLU fused, MFMA. One block per image. Dynamic LDS 132352 B.
// ---------------------------------------------------------------------------
#define CONV2_LDS 132352
__global__ __launch_bounds__(512, 1) void conv2_fused(
    const short* __restrict__ h1pad, const short* __restrict__ afc2,
    const float* __restrict__ bias,
    const float* __restrict__ g2w, const float* __restrict__ g2b,
    short* __restrict__ h2pad)
{
    extern __shared__ char smem[];
    char*  sin    = smem;                        // 131072
    float* gnred  = (float*)(smem + 131072);     // 128
    float* gnq    = (float*)(smem + 131584);     // 128
    float* s_mean = (float*)(smem + 132096);     // 32
    float* s_rstd = (float*)(smem + 132224);     // 32

    const int t = threadIdx.x, b = blockIdx.x;
    const int w = t >> 6, l = t & 63, lhi = (l >> 4) & 3, llo = l & 15;
    const int mt = w >> 1, half = w & 1;
    const int oc0 = mt*16 + lhi*4;

    {
        const uint4* src = (const uint4*)((const char*)h1pad + (size_t)b*131072);
        uint4* dst = (uint4*)sin;
        for (int i = t; i < 8192; i += 512) dst[i] = src[i];
    }
    bf16x8 aw[32];
    #pragma unroll
    for (int kt = 0; kt < 32; ++kt)
        aw[kt] = *(const bf16x8*)(afc2 + ((size_t)((mt*32 + kt)*64 + l))*8);
    f32x4 bia = *(const f32x4*)&bias[oc0];
    __syncthreads();

    f32x4 acc[8];
    #pragma unroll
    for (int i = 0; i < 8; ++i) acc[i] = (f32x4){0.f,0.f,0.f,0.f};

    #pragma unroll
    for (int i = 0; i < 8; ++i) {
        const int nt = half*8 + i;
        if (nt > 14) continue;
        const int n = nt*16 + llo;
        const int p = n < 225 ? n : 224;
        const int oy = p/15, ox = p%15;
        #pragma unroll
        for (int kt = 0; kt < 32; ++kt) {
            const int tap = kt >> 1;
            const int ky = tap >> 2, kx = tap & 3;
            const int pidx = (oy*2 + ky)*32 + (ox*2 + kx);
            const int ico = (kt & 1)*32 + lhi*8;
            const int byte = (pidx*128 + ico*2) ^ (((pidx>>1)&7) << 4);
            bf16x8 bb = *(const bf16x8*)(sin + byte);
            acc[i] = __builtin_amdgcn_mfma_f32_16x16x32_bf16(aw[kt], bb, acc[i], 0, 0, 0);
        }
    }

    float s[4] = {0,0,0,0}, q[4] = {0,0,0,0};
    #pragma unroll
    for (int i = 0; i < 8; ++i) {
        const int nt = half*8 + i;
        if (nt > 14) continue;
        const int n = nt*16 + llo;
        #pragma unroll
        for (int r = 0; r < 4; ++r) {
            float v = acc[i][r] + bia[r];
            acc[i][r] = v;
            if (n < 225) { s[r] += v; q[r] += v*v; }
        }
    }
    #pragma unroll
    for (int off = 1; off < 16; off <<= 1) {
        #pragma unroll
        for (int r = 0; r < 4; ++r) {
            s[r] += __shfl_xor(s[r], off);
            q[r] += __shfl_xor(q[r], off);
        }
    }
    if (llo == 0) {
        #pragma unroll
        for (int r = 0; r < 4; ++r) {
            gnred[w*16 + lhi*4 + r] = s[r];
            gnq[w*16 + lhi*4 + r]   = q[r];
        }
    }
    __syncthreads();
    if (t < 32) {
        const int oc = t*2;
        const int mtg = oc >> 4, lh = (oc >> 2) & 3, r0 = oc & 3;
        const int i0 = (mtg*2)*16 + lh*4 + r0;
        float ss = gnred[i0] + gnred[i0+1] + gnred[i0+16] + gnred[i0+17];
        float qq = gnq[i0]   + gnq[i0+1]   + gnq[i0+16]   + gnq[i0+17];
        float m = ss * (1.f/450.f);
        float var = qq * (1.f/450.f) - m*m;
        s_mean[t] = m; s_rstd[t] = rsqrtf(var + 1e-5f);
    }
    __syncthreads();

    const int g0 = oc0 >> 1;
    const float m0 = s_mean[g0],   rs0 = s_rstd[g0];
    const float m1 = s_mean[g0+1], rs1 = s_rstd[g0+1];
    const float w0 = g2w[oc0], w1v = g2w[oc0+1], w2v = g2w[oc0+2], w3v = g2w[oc0+3];
    const float b0 = g2b[oc0], b1v_ = g2b[oc0+1], b2v_ = g2b[oc0+2], b3v_ = g2b[oc0+3];
    char* hb2 = (char*)h2pad + (size_t)b*36992;

    #pragma unroll
    for (int i = 0; i < 8; ++i) {
        const int nt = half*8 + i;
        if (nt > 14) continue;
        const int n = nt*16 + llo;
        if (n >= 225) continue;
        const int pidx = (n/15 + 1)*17 + (n%15 + 1);
        float v0 = fmaxf((acc[i][0]-m0)*rs0*w0  + b0,   0.f);
        float v1 = fmaxf((acc[i][1]-m0)*rs0*w1v + b1v_, 0.f);
        float v2 = fmaxf((acc[i][2]-m1)*rs1*w2v + b2v_, 0.f);
        float v3 = fmaxf((acc[i][3]-m1)*rs1*w3v + b3v_, 0.f);
        uint2 pk; pk.x = f2bf2(v0, v1); pk.y = f2bf2(v2, v3);
        int byte = (pidx*128 + oc0*2) ^ (((pidx>>1)&7) << 4);
        *(uint2*)(hb2 + byte) = pk;
    }
    for (int u = t; u < 512; u += 512) {
        const int bp = u >> 3, slot = u & 7;
        int pidx;
        if (bp < 17) pidx = bp;
        else if (bp < 34) pidx = 16*17 + (bp - 17);
        else if (bp < 49) pidx = (bp - 34 + 1)*17;
        else pidx = (bp - 49 + 1)*17 + 16;
        uint4 z; z.x = z.y = z.z = z.w = 0u;
        *(uint4*)(hb2 + pidx*128 + slot*16) = z;
    }
}

// ---------------------------------------------------------------------------
// conv3 MFMA -> y fp32. One block per image.
// ---------------------------------------------------------------------------
__global__ __launch_bounds__(512, 1) void conv3_mfma(
    const short* __restrict__ h2pad, const short* __restrict__ afc3,
    const float* __restrict__ bias, float* __restrict__ y)
{
    __shared__ __align__(16) char sin[36992];
    const int t = threadIdx.x, b = blockIdx.x;
    const int w = t >> 6, l = t & 63, lhi = (l >> 4) & 3, llo = l & 15;
    const int mt = w >> 1, half = w & 1;
    const int oc0 = mt*16 + lhi*4;

    {
        const uint4* src = (const uint4*)((const char*)h2pad + (size_t)b*36992);
        uint4* dst = (uint4*)sin;
        for (int i = t; i < 2312; i += 512) dst[i] = src[i];
    }
    bf16x8 aw[32];
    #pragma unroll
    for (int kt = 0; kt < 32; ++kt)
        aw[kt] = *(const bf16x8*)(afc3 + ((size_t)((mt*32 + kt)*64 + l))*8);
    f32x4 bia = *(const f32x4*)&bias[oc0];
    __syncthreads();

    f32x4 acc[2];
    acc[0] = (f32x4){0.f,0.f,0.f,0.f};
    acc[1] = (f32x4){0.f,0.f,0.f,0.f};
    #pragma unroll
    for (int i = 0; i < 2; ++i) {
        const int nt = half*2 + i;
        const int n = nt*16 + llo;
        const int p = n < 49 ? n : 48;
        const int oy = p/7, ox = p%7;
        #pragma unroll
        for (int kt = 0; kt < 32; ++kt) {
            const int tap = kt >> 1;
            const int ky = tap >> 2, kx = tap & 3;
            const int pidx = (oy*2 + ky)*17 + (ox*2 + kx);
            const int ico = (kt & 1)*32 + lhi*8;
            const int byte = (pidx*128 + ico*2) ^ (((pidx>>1)&7) << 4);
            bf16x8 bb = *(const bf16x8*)(sin + byte);
            acc[i] = __builtin_amdgcn_mfma_f32_16x16x32_bf16(aw[kt], bb, acc[i], 0, 0, 0);
        }
    }
    #pragma unroll
    for (int i = 0; i < 2; ++i) {
        const int n = (half*2 + i)*16 + llo;
        if (n < 49) {
            #pragma unroll
            for (int r = 0; r < 4; ++r)
                y[(size_t)b*NELEM + (oc0 + r)*49 + n] = acc[i][r] + bia[r];
        }
    }
}

// ---------------------------------------------------------------------------
// In-register GN reduce helper (from round 2, verified)
// ---------------------------------------------------------------------------
__device__ __forceinline__ void gn_inreg(
    const float v0[4], const float v1[4], bool vA, bool vB,
    int w, int lhi, int llo, int t,
    float* gnred, float* s_mean, float* s_rstd)
{
    float s0 = 0.f, q0 = 0.f, s1 = 0.f, q1 = 0.f;
    if (vA) {
        s0 += v0[0] + v0[1]; q0 += v0[0]*v0[0] + v0[1]*v0[1];
        s1 += v0[2] + v0[3]; q1 += v0[2]*v0[2] + v0[3]*v0[3];
    }
    if (vB) {
        s0 += v1[0] + v1[1]; q0 += v1[0]*v1[0] + v1[1]*v1[1];
        s1 += v1[2] + v1[3]; q1 += v1[2]*v1[2] + v1[3]*v1[3];
    }
    #pragma unroll
    for (int off = 1; off < 16; off <<= 1) {
        s0 += __shfl_xor(s0, off); q0 += __shfl_xor(q0, off);
        s1 += __shfl_xor(s1, off); q1 += __shfl_xor(q1, off);
    }
    if (llo == 0) {
        float* gp = gnred + w*16 + lhi*4;
        gp[0] = s0; gp[1] = q0; gp[2] = s1; gp[3] = q1;
    }
    __syncthreads();
    if (t < 32) {
        const int mtg = t >> 3, qq = (t >> 1) & 3, hh = t & 1;
        const int i0 = (mtg*2)*16 + qq*4 + hh*2;
        const int i1 = i0 + 16;
        float s  = gnred[i0]   + gnred[i1];
        float q  = gnred[i0+1] + gnred[i1+1];
        float m  = s * (1.f/98.f);
        float var = q * (1.f/98.f) - m*m;
        s_mean[t] = m;
        s_rstd[t] = rsqrtf(var + 1e-5f);
    }
    __syncthreads();
}

// ---------------------------------------------------------------------------
// The whole ODE (6 dopri5 steps, 36 f-evals) + head, one block per image.
// Dynamic LDS 114752 B.
// ---------------------------------------------------------------------------
#define ODE_LDS 114752
__global__ __launch_bounds__(512, 1) void ode_head(
    const float* __restrict__ yin,
    const short* __restrict__ af1, const short* __restrict__ af2,
    const float* __restrict__ stab1, const float* __restrict__ stab2,
    const float* __restrict__ b1v, const float* __restrict__ b2v,
    const float* __restrict__ oaw, const float* __restrict__ oab,
    const float* __restrict__ obw, const float* __restrict__ obb,
    const float* __restrict__ ocw, const float* __restrict__ ocb,
    const float* __restrict__ g3w, const float* __restrict__ g3b,
    const float* __restrict__ linw, const float* __restrict__ linb,
    float* __restrict__ out)
{
    extern __shared__ char smem[];
    float* y_l    = (float*)smem;                  // 3136
    float* kbuf   = (float*)(smem + 12544);        // 5*3136
    float* scr    = (float*)(smem + 75264);        // 3136
    char*  act0   = smem + 87808;                  // 81*160
    char*  act1   = smem + 87808 + 12960;          // 81*160
    float* gnred  = (float*)(smem + 113728);       // 128
    float* s_mean = (float*)(smem + 114240);       // 32
    float* s_rstd = (float*)(smem + 114368);       // 32
    float* s_cm   = (float*)(smem + 114496);       // 64

    const int t = threadIdx.x, b = blockIdx.x;
    const int w = t >> 6, l = t & 63, lhi = (l >> 4) & 3, llo = l & 15;
    const int mt = w >> 1;
    const int ntA = (w & 1)*2, ntB = ntA + 1;
    const int nA = ntA*16 + llo, nB = ntB*16 + llo;
    const bool vA = nA < 49, vB = nB < 49;
    const int nsA = vA ? nA : 48, nsB = vB ? nB : 48;
    const int paA = (nsA/7 + 1)*9 + (nsA%7 + 1);
    const int paB = (nsB/7 + 1)*9 + (nsB%7 + 1);
    const int oc0 = mt*16 + lhi*4;

    for (int i = t; i < 3136; i += 512) y_l[i] = yin[(size_t)b*NELEM + i];
    for (int i = t; i < 6480; i += 512) {
        ((unsigned*)act0)[i] = 0u;   // zeros both act buffers (contiguous)
    }
    bf16x8 aw1[18], aw2[18];
    #pragma unroll
    for (int kt = 0; kt < 18; ++kt) {
        aw1[kt] = *(const bf16x8*)(af1 + ((size_t)(mt*18 + kt)*64 + l)*8);
        aw2[kt] = *(const bf16x8*)(af2 + ((size_t)(mt*18 + kt)*64 + l)*8);
    }
    __syncthreads();

    const float hf  = (float)(1.0/6.0);
    const float C10 = (float)((1.0/6.0)*(1.0/5.0));
    const float C20 = (float)((1.0/6.0)*(3.0/40.0)),  C21 = (float)((1.0/6.0)*(9.0/40.0));
    const float C30 = (float)((1.0/6.0)*(44.0/45.0)), C31 = (float)((1.0/6.0)*(-56.0/15.0)), C32 = (float)((1.0/6.0)*(32.0/9.0));
    const float C40 = (float)((1.0/6.0)*(19372.0/6561.0)), C41 = (float)((1.0/6.0)*(-25360.0/2187.0)),
                C42 = (float)((1.0/6.0)*(64448.0/6561.0)), C43 = (float)((1.0/6.0)*(-212.0/729.0));
    const float C50 = (float)((1.0/6.0)*(9017.0/3168.0)), C51 = (float)((1.0/6.0)*(-355.0/33.0)),
                C52 = (float)((1.0/6.0)*(46732.0/5247.0)), C53 = (float)((1.0/6.0)*(49.0/176.0)),
                C54 = (float)((1.0/6.0)*(-5103.0/18656.0));
    const float B0 = (float)((1.0/6.0)*(35.0/384.0)), B2c = (float)((1.0/6.0)*(500.0/1113.0)),
                B3c = (float)((1.0/6.0)*(125.0/192.0)), B4c = (float)((1.0/6.0)*(-2187.0/6784.0)),
                B5c = (float)((1.0/6.0)*(11.0/84.0));

    for (int step = 0; step < 6; ++step) {
        const float t0 = (float)step * hf;
        for (int stage = 0; stage < 6; ++stage) {
            float cA=0.f, cB=0.f, cC=0.f, cD=0.f, cE=0.f, tf=0.f;
            if (stage == 1)      { cA=C10; tf = 0.2f; }
            else if (stage == 2) { cA=C20; cB=C21; tf = 0.3f; }
            else if (stage == 3) { cA=C30; cB=C31; cC=C32; tf = 0.8f; }
            else if (stage == 4) { cA=C40; cB=C41; cC=C42; cD=C43; tf = (float)(8.0/9.0); }
            else if (stage == 5) { cA=C50; cB=C51; cC=C52; cD=C53; cE=C54; tf = 1.f; }
            const float tval = t0 + hf*tf;

            // ---- stage combine + GN_oa stats ----
            {
                const int g = t >> 4, sub = t & 15;
                float s = 0.f, q = 0.f;
                for (int e = sub; e < 98; e += 16) {
                    const int i = g*98 + e;
                    float v = y_l[i];
                    if (stage > 0) v = fmaf(cA, kbuf[i], v);
                    if (stage > 1) v = fmaf(cB, kbuf[3136 + i], v);
                    if (stage > 2) v = fmaf(cC, kbuf[2*3136 + i], v);
                    if (stage > 3) v = fmaf(cD, kbuf[3*3136 + i], v);
                    if (stage > 4) v = fmaf(cE, kbuf[4*3136 + i], v);
                    scr[i] = v;
                    s += v; q += v*v;
                }
                s += __shfl_xor(s,1); q += __shfl_xor(q,1);
                s += __shfl_xor(s,2); q += __shfl_xor(q,2);
                s += __shfl_xor(s,4); q += __shfl_xor(q,4);
                s += __shfl_xor(s,8); q += __shfl_xor(q,8);
                if (sub == 0) {
                    float m = s * (1.f/98.f);
                    float var = q * (1.f/98.f) - m*m;
                    s_mean[g] = m; s_rstd[g] = rsqrtf(var + 1e-5f);
                }
            }
            __syncthreads();
            // ---- normalize + relu -> act0 ----
            for (int idx = t; idx < 1568; idx += 512) {
                const int p = idx >> 5, c = idx & 31;
                const int ch = c*2;
                const float m = s_mean[c], r = s_rstd[c];
                float x0 = fmaxf((scr[ch*49 + p]      - m)*r*oaw[ch]   + oab[ch],   0.f);
                float x1 = fmaxf((scr[ch*49 + 49 + p] - m)*r*oaw[ch+1] + oab[ch+1], 0.f);
                const int pa = (p/7 + 1)*9 + (p%7 + 1);
                const int byte = pa*160 + (((ch>>3) ^ (pa&7)) << 4) + ((ch&7) << 1);
                *(unsigned*)(act0 + byte) = f2bf2(x0, x1);
            }
            __syncthreads();

            // ---- conv1 MFMA ----
            f32x4 acc0 = {0.f,0.f,0.f,0.f}, acc1 = {0.f,0.f,0.f,0.f};
            #pragma unroll
            for (int kt = 0; kt < 18; ++kt) {
                const int tap = kt >> 1;
                const int d = (tap/3 - 1)*9 + (tap%3 - 1);
                const int ico = (kt & 1)*32 + lhi*8;
                const int pA = paA + d, pB = paB + d;
                bf16x8 bb0 = *(const bf16x8*)(act0 + pA*160 + (((ico>>3) ^ (pA&7)) << 4));
                bf16x8 bb1 = *(const bf16x8*)(act0 + pB*160 + (((ico>>3) ^ (pB&7)) << 4));
                acc0 = __builtin_amdgcn_mfma_f32_16x16x32_bf16(aw1[kt], bb0, acc0, 0, 0, 0);
                acc1 = __builtin_amdgcn_mfma_f32_16x16x32_bf16(aw1[kt], bb1, acc1, 0, 0, 0);
            }
            float v0[4], v1[4];
            {
                f32x4 bia = *(const f32x4*)&b1v[oc0];
                #pragma unroll
                for (int r = 0; r < 4; ++r) {
                    v0[r] = acc0[r] + bia[r] + tval * stab1[(oc0 + r)*49 + nsA];
                    v1[r] = acc1[r] + bia[r] + tval * stab1[(oc0 + r)*49 + nsB];
                }
            }
            gn_inreg(v0, v1, vA, vB, w, lhi, llo, t, gnred, s_mean, s_rstd);
            {
                f32x4 gww = *(const f32x4*)&obw[oc0];
                f32x4 gbb = *(const f32x4*)&obb[oc0];
                const int g0 = oc0 >> 1;
                const float m0 = s_mean[g0],   r0 = s_rstd[g0];
                const float m1 = s_mean[g0+1], r1 = s_rstd[g0+1];
                v0[0] = fmaxf((v0[0]-m0)*r0*gww[0]+gbb[0], 0.f);
                v0[1] = fmaxf((v0[1]-m0)*r0*gww[1]+gbb[1], 0.f);
                v0[2] = fmaxf((v0[2]-m1)*r1*gww[2]+gbb[2], 0.f);
                v0[3] = fmaxf((v0[3]-m1)*r1*gww[3]+gbb[3], 0.f);
                v1[0] = fmaxf((v1[0]-m0)*r0*gww[0]+gbb[0], 0.f);
                v1[1] = fmaxf((v1[1]-m0)*r0*gww[1]+gbb[1], 0.f);
                v1[2] = fmaxf((v1[2]-m1)*r1*gww[2]+gbb[2], 0.f);
                v1[3] = fmaxf((v1[3]-m1)*r1*gww[3]+gbb[3], 0.f);
                if (vA) {
                    uint2 pk; pk.x = f2bf2(v0[0], v0[1]); pk.y = f2bf2(v0[2], v0[3]);
                    const int byte = paA*160 + (((oc0>>3) ^ (paA&7)) << 4) + ((oc0&7) << 1);
                    *(uint2*)(act1 + byte) = pk;
                }
                if (vB) {
                    uint2 pk; pk.x = f2bf2(v1[0], v1[1]); pk.y = f2bf2(v1[2], v1[3]);
                    const int byte = paB*160 + (((oc0>>3) ^ (paB&7)) << 4) + ((oc0&7) << 1);
                    *(uint2*)(act1 + byte) = pk;
                }
            }
            __syncthreads();

            // ---- conv2 MFMA ----
            acc0 = (f32x4){0.f,0.f,0.f,0.f};
            acc1 = (f32x4){0.f,0.f,0.f,0.f};
            #pragma unroll
            for (int kt = 0; kt < 18; ++kt) {
                const int tap = kt >> 1;
                const int d = (tap/3 - 1)*9 + (tap%3 - 1);
                const int ico = (kt & 1)*32 + lhi*8;
                const int pA = paA + d, pB = paB + d;
                bf16x8 bb0 = *(const bf16x8*)(act1 + pA*160 + (((ico>>3) ^ (pA&7)) << 4));
                bf16x8 bb1 = *(const bf16x8*)(act1 + pB*160 + (((ico>>3) ^ (pB&7)) << 4));
                acc0 = __builtin_amdgcn_mfma_f32_16x16x32_bf16(aw2[kt], bb0, acc0, 0, 0, 0);
                acc1 = __builtin_amdgcn_mfma_f32_16x16x32_bf16(aw2[kt], bb1, acc1, 0, 0, 0);
            }
            {
                f32x4 bia = *(const f32x4*)&b2v[oc0];
                #pragma unroll
                for (int r = 0; r < 4; ++r) {
                    v0[r] = acc0[r] + bia[r] + tval * stab2[(oc0 + r)*49 + nsA];
                    v1[r] = acc1[r] + bia[r] + tval * stab2[(oc0 + r)*49 + nsB];
                }
            }
            gn_inreg(v0, v1, vA, vB, w, lhi, llo, t, gnred, s_mean, s_rstd);
            {
                f32x4 gww = *(const f32x4*)&ocw[oc0];
                f32x4 gbb = *(const f32x4*)&ocb[oc0];
                const int g0 = oc0 >> 1;
                const float m0 = s_mean[g0],   r0 = s_rstd[g0];
                const float m1 = s_mean[g0+1], r1 = s_rstd[g0+1];
                float* kdst = (stage < 5) ? (kbuf + stage*3136) : scr;
                if (vA) {
                    kdst[(oc0+0)*49 + nA] = (v0[0]-m0)*r0*gww[0]+gbb[0];
                    kdst[(oc0+1)*49 + nA] = (v0[1]-m0)*r0*gww[1]+gbb[1];
                    kdst[(oc0+2)*49 + nA] = (v0[2]-m1)*r1*gww[2]+gbb[2];
                    kdst[(oc0+3)*49 + nA] = (v0[3]-m1)*r1*gww[3]+gbb[3];
                }
                if (vB) {
                    kdst[(oc0+0)*49 + nB] = (v1[0]-m0)*r0*gww[0]+gbb[0];
                    kdst[(oc0+1)*49 + nB] = (v1[1]-m0)*r0*gww[1]+gbb[1];
                    kdst[(oc0+2)*49 + nB] = (v1[2]-m1)*r1*gww[2]+gbb[2];
                    kdst[(oc0+3)*49 + nB] = (v1[3]-m1)*r1*gww[3]+gbb[3];
                }
            }
            __syncthreads();

            if (stage == 5) {
                for (int i = t; i < 3136; i += 512) {
                    float v = y_l[i];
                    v = fmaf(B0,  kbuf[i], v);
                    v = fmaf(B2c, kbuf[2*3136 + i], v);
                    v = fmaf(B3c, kbuf[3*3136 + i], v);
                    v = fmaf(B4c, kbuf[4*3136 + i], v);
                    v = fmaf(B5c, scr[i], v);
                    y_l[i] = v;
                }
                __syncthreads();
            }
        }
    }

    // ---- head: GN(g3)+ReLU -> spatial mean -> linear ----
    {
        const int g = t >> 4, sub = t & 15;
        float s = 0.f, q = 0.f;
        for (int e = sub; e < 98; e += 16) {
            float v = y_l[g*98 + e];
            s += v; q += v*v;
        }
        s += __shfl_xor(s,1); q += __shfl_xor(q,1);
        s += __shfl_xor(s,2); q += __shfl_xor(q,2);
        s += __shfl_xor(s,4); q += __shfl_xor(q,4);
        s += __shfl_xor(s,8); q += __shfl_xor(q,8);
        if (sub == 0) {
            float m = s * (1.f/98.f);
            float var = q * (1.f/98.f) - m*m;
            s_mean[g] = m; s_rstd[g] = rsqrtf(var + 1e-5f);
        }
    }
    __syncthreads();
    if (t < 64) {
        const int ch = t, g = ch >> 1;
        const float m = s_mean[g], r = s_rstd[g];
        const float ww = g3w[ch], bb = g3b[ch];
        float sum = 0.f;
        for (int p = 0; p < 49; ++p) {
            float v = (y_l[ch*49 + p] - m)*r*ww + bb;
            sum += fmaxf(v, 0.f);
        }
        s_cm[ch] = sum * (1.f/49.f);
    }
    __syncthreads();
    if (t < 10) {
        float a = linb[t];
        for (int c = 0; c < 64; ++c) a = fmaf(s_cm[c], linw[t*64 + c], a);
        out[b*10 + t] = a;
    }
}

// ---------------------------------------------------------------------------
// Host launch
// ---------------------------------------------------------------------------
extern "C" void kernel_launch(void* const* d_in, const int* in_sizes, int n_in,
                              void* d_out, int out_size, void* d_ws, size_t ws_size,
                              hipStream_t stream)
{
    const float* x      = (const float*)d_in[0];
    const float* c1_w   = (const float*)d_in[1];
    const float* c1_b   = (const float*)d_in[2];
    const float* g1_w   = (const float*)d_in[3];
    const float* g1_b   = (const float*)d_in[4];
    const float* c2_w   = (const float*)d_in[5];
    const float* c2_b   = (const float*)d_in[6];
    const float* g2_w   = (const float*)d_in[7];
    const float* g2_b   = (const float*)d_in[8];
    const float* c3_w   = (const float*)d_in[9];
    const float* c3_b   = (const float*)d_in[10];
    const float* oa_w   = (const float*)d_in[11];
    const float* oa_b   = (const float*)d_in[12];
    const float* occ1_w = (const float*)d_in[13];
    const float* occ1_b = (const float*)d_in[14];
    const float* ob_w   = (const float*)d_in[15];
    const float* ob_b   = (const float*)d_in[16];
    const float* occ2_w = (const float*)d_in[17];
    const float* occ2_b = (const float*)d_in[18];
    const float* oc_w   = (const float*)d_in[19];
    const float* oc_b   = (const float*)d_in[20];
    const float* g3_w   = (const float*)d_in[21];
    const float* g3_b   = (const float*)d_in[22];
    const float* lin_w  = (const float*)d_in[23];
    const float* lin_b  = (const float*)d_in[24];
    float* out = (float*)d_out;

    float* ws = (float*)d_ws;
    size_t off = 0;
    float* y     = ws + off; off += 802816;
    float* stab1 = ws + off; off += 3136;
    float* stab2 = ws + off; off += 3136;
    short* af1   = (short*)(ws + off); off += 18432;   // 36864 shorts
    short* af2   = (short*)(ws + off); off += 18432;
    short* afc1  = (short*)(ws + off); off += 1024;    // 2048 shorts
    short* afc2  = (short*)(ws + off); off += 32768;   // 65536 shorts
    short* afc3  = (short*)(ws + off); off += 32768;
    short* h1pad = (short*)(ws + off); off += 8388608; // 256*65536 shorts
    short* h2pad = (short*)(ws + off); off += 2367488; // 256*18496 shorts

    // prep (weights constant per launch)
    prep_afrag_kernel<<<dim3(144, 2), 256, 0, stream>>>(occ1_w, occ2_w, af1, af2);
    prep_stab_kernel<<<dim3(13, 2), 256, 0, stream>>>(occ1_w, occ2_w, stab1, stab2);
    prep_c1frag_kernel<<<8, 256, 0, stream>>>(c1_w, afc1);
    prep_c23frag_kernel<<<dim3(256, 2), 256, 0, stream>>>(c2_w, c3_w, afc2, afc3);

    // preamble CNN (fused, per-image MFMA)
    conv1_fused<<<B, 512, 0, stream>>>(x, afc1, c1_b, g1_w, g1_b, h1pad);
    conv2_fused<<<B, 512, CONV2_LDS, stream>>>(h1pad, afc2, c2_b, g2_w, g2_b, h2pad);
    conv3_mfma<<<B, 512, 0, stream>>>(h2pad, afc3, c3_b, y);

    // full ODE + head, one launch
    ode_head<<<B, 512, ODE_LDS, stream>>>(y, af1, af2, stab1, stab2,
        occ1_b, occ2_b, oa_w, oa_b, ob_w, ob_b, oc_w, oc_b,
        g3_w, g3_b, lin_w, lin_b, out);
}

// Round 4
// 251.721 us; speedup vs baseline: 11.9957x; 1.6357x over previous
//
#include <hip/hip_runtime.h>
#include <hip/hip_bf16.h>

#define B 256
#define NELEM 3136          // 64*49 per image
#define TOTAL (B*NELEM)

typedef __attribute__((ext_vector_type(8))) short bf16x8;
typedef __attribute__((ext_vector_type(4))) float f32x4;

#define MFMA16(a,b,c) __builtin_amdgcn_mfma_f32_16x16x32_bf16((a),(b),(c),0,0,0)

__device__ __forceinline__ unsigned short f2bf(float f) {
    unsigned u = __float_as_uint(f);
    unsigned r = (u + 0x7fffu + ((u >> 16) & 1u)) >> 16;
    return (unsigned short)r;
}
__device__ __forceinline__ unsigned int f2bf2(float lo, float hi) {
    return (unsigned int)f2bf(lo) | ((unsigned int)f2bf(hi) << 16);
}

// lane-tile -> pixel permutation: each 16-lane tile has exactly 2 pixels of
// each (pa mod 8) residue class -> conflict-free conv ds_read_b128.
__device__ const int d_sigma[64] = {
    6,12,13,19,0,20,1,7,2,8,3,9,4,10,5,11,
    18,24,25,31,26,32,27,33,14,34,15,21,16,22,17,23,
    30,36,37,43,38,44,39,45,40,46,41,47,28,48,29,35,
    42,42,42,42,42,42,42,42,42,42,42,42,42,42,42,42
};

// ---------------------------------------------------------------------------
// Weight-fragment prep kernels (unchanged layouts)
// ---------------------------------------------------------------------------
__global__ __launch_bounds__(256) void prep_afrag_kernel(
    const float* __restrict__ w1, const float* __restrict__ w2,
    short* __restrict__ af1, short* __restrict__ af2)
{
    const int e = blockIdx.x * 256 + threadIdx.x;   // < 36864
    const float* W = blockIdx.y ? w2 : w1;
    short* dst = blockIdx.y ? af2 : af1;
    const int j = e & 7;
    const int lane = (e >> 3) & 63;
    const int kt = (e >> 9) % 18;
    const int mt = (e >> 9) / 18;
    const int m = mt*16 + (lane & 15);
    const int k = kt*32 + ((lane >> 4) & 3)*8 + j;
    const int tap = k >> 6;
    const int ic  = k & 63;
    dst[e] = (short)f2bf(W[m*585 + (ic + 1)*9 + tap]);
}

__global__ __launch_bounds__(256) void prep_stab_kernel(
    const float* __restrict__ w1, const float* __restrict__ w2,
    float* __restrict__ stab1, float* __restrict__ stab2)
{
    const int id = blockIdx.x * 256 + threadIdx.x;
    if (id >= 3136) return;
    const float* W = blockIdx.y ? w2 : w1;
    float* dst = blockIdx.y ? stab2 : stab1;
    const int oc = id / 49, p = id % 49;
    const int py = p / 7, px = p % 7;
    float s = 0.f;
    #pragma unroll
    for (int ky = 0; ky < 3; ++ky) {
        int iy = py - 1 + ky;
        if (iy < 0 || iy > 6) continue;
        #pragma unroll
        for (int kx = 0; kx < 3; ++kx) {
            int ix = px - 1 + kx;
            if (ix < 0 || ix > 6) continue;
            s += W[oc*585 + ky*3 + kx];
        }
    }
    dst[id] = s;
}

__global__ __launch_bounds__(256) void prep_c1frag_kernel(
    const float* __restrict__ w1, short* __restrict__ afc1)
{
    const int e = blockIdx.x * 256 + threadIdx.x;   // < 2048
    const int j = e & 7, lane = (e >> 3) & 63, mtq = e >> 9;
    const int m = mtq*16 + (lane & 15);
    const int k = ((lane >> 4) & 3)*8 + j;
    float v = (k < 27) ? w1[m*27 + k] : 0.f;
    afc1[e] = (short)f2bf(v);
}

__global__ __launch_bounds__(256) void prep_c23frag_kernel(
    const float* __restrict__ w2, const float* __restrict__ w3,
    short* __restrict__ afc2, short* __restrict__ afc3)
{
    const int e = blockIdx.x * 256 + threadIdx.x;   // < 65536
    const float* W = blockIdx.y ? w3 : w2;
    short* dst = blockIdx.y ? afc3 : afc2;
    const int j = e & 7, lane = (e >> 3) & 63, kt = (e >> 9) & 31, mtq = e >> 14;
    const int m = mtq*16 + (lane & 15);
    const int k = kt*32 + ((lane >> 4) & 3)*8 + j;
    const int tap = k >> 6, ic = k & 63;
    dst[e] = (short)f2bf(W[m*1024 + ic*16 + tap]);
}

// ---------------------------------------------------------------------------
// conv1 + GN1 + ReLU fused. Output h1pad: [8 c8][1025 pix(32x32 pad)][16B]
// per image 131200 B. 1025 = 1 mod 8 -> conflict-free strided reads downstream.
// ---------------------------------------------------------------------------
__global__ __launch_bounds__(512, 1) void conv1_fused(
    const float* __restrict__ x, const short* __restrict__ afc1,
    const float* __restrict__ bias,
    const float* __restrict__ g1w, const float* __restrict__ g1b,
    short* __restrict__ h1pad)
{
    __shared__ float xs[3072];
    __shared__ float gnred[128], gnq[128];
    __shared__ float s_mean[32], s_rstd[32];

    const int t = threadIdx.x, b = blockIdx.x;
    const int w = t >> 6, l = t & 63, lhi = (l >> 4) & 3, llo = l & 15;
    const int mt = w & 3, sub = w >> 2;
    const int oc0 = mt*16 + lhi*4;

    for (int i = t; i < 3072; i += 512) xs[i] = x[b*3072 + i];

    bf16x8 afr = *(const bf16x8*)(afc1 + ((size_t)(mt*64 + l))*8);

    int boff[8]; bool bval[8];
    #pragma unroll
    for (int j = 0; j < 8; ++j) {
        int k = lhi*8 + j;
        bval[j] = (k < 27);
        int kk = bval[j] ? k : 0;
        int c = kk / 9, tap = kk % 9;
        boff[j] = c*1024 + (tap/3)*32 + (tap%3);
    }
    f32x4 bia = *(const f32x4*)&bias[oc0];
    __syncthreads();

    f32x4 acc[29];
    float s[4] = {0,0,0,0}, q[4] = {0,0,0,0};
    #pragma unroll
    for (int i = 0; i < 29; ++i) {
        const int nt = sub*29 + i;
        f32x4 a = {0.f,0.f,0.f,0.f};
        if (nt < 57) {
            const int p = nt*16 + llo;
            const int pc = p < 900 ? p : 899;
            const int base = (pc/30)*32 + (pc%30);
            union { bf16x8 v; unsigned u[4]; } bb;
            #pragma unroll
            for (int jj = 0; jj < 4; ++jj) {
                float e0 = bval[2*jj]   ? xs[boff[2*jj]   + base] : 0.f;
                float e1 = bval[2*jj+1] ? xs[boff[2*jj+1] + base] : 0.f;
                bb.u[jj] = f2bf2(e0, e1);
            }
            a = MFMA16(afr, bb.v, a);
            #pragma unroll
            for (int r = 0; r < 4; ++r) {
                a[r] += bia[r];
                if (p < 900) { s[r] += a[r]; q[r] += a[r]*a[r]; }
            }
        }
        acc[i] = a;
    }

    #pragma unroll
    for (int off = 1; off < 16; off <<= 1) {
        #pragma unroll
        for (int r = 0; r < 4; ++r) {
            s[r] += __shfl_xor(s[r], off);
            q[r] += __shfl_xor(q[r], off);
        }
    }
    if (llo == 0) {
        #pragma unroll
        for (int r = 0; r < 4; ++r) {
            gnred[w*16 + lhi*4 + r] = s[r];
            gnq[w*16 + lhi*4 + r]   = q[r];
        }
    }
    __syncthreads();
    if (t < 32) {
        const int oc = t*2;
        const int mtg = oc >> 4, lh = (oc >> 2) & 3, r0 = oc & 3;
        const int i0 = mtg*16 + lh*4 + r0;
        float ss = gnred[i0] + gnred[i0+1] + gnred[i0+64] + gnred[i0+65];
        float qq = gnq[i0]   + gnq[i0+1]   + gnq[i0+64]   + gnq[i0+65];
        float m = ss * (1.f/1800.f);
        float var = qq * (1.f/1800.f) - m*m;
        s_mean[t] = m; s_rstd[t] = rsqrtf(var + 1e-5f);
    }
    __syncthreads();

    const int g0 = oc0 >> 1;
    const float m0 = s_mean[g0],   rs0 = s_rstd[g0];
    const float m1 = s_mean[g0+1], rs1 = s_rstd[g0+1];
    const float w0 = g1w[oc0], w1v = g1w[oc0+1], w2v = g1w[oc0+2], w3v = g1w[oc0+3];
    const float b0 = g1b[oc0], b1v_ = g1b[oc0+1], b2v_ = g1b[oc0+2], b3v_ = g1b[oc0+3];
    char* hb = (char*)h1pad + (size_t)b*131200;

    #pragma unroll
    for (int i = 0; i < 29; ++i) {
        const int nt = sub*29 + i;
        if (nt >= 57) continue;
        const int p = nt*16 + llo;
        if (p >= 900) continue;
        const int pidx = (p/30 + 1)*32 + (p%30 + 1);
        float v0 = fmaxf((acc[i][0]-m0)*rs0*w0  + b0,   0.f);
        float v1 = fmaxf((acc[i][1]-m0)*rs0*w1v + b1v_, 0.f);
        float v2 = fmaxf((acc[i][2]-m1)*rs1*w2v + b2v_, 0.f);
        float v3 = fmaxf((acc[i][3]-m1)*rs1*w3v + b3v_, 0.f);
        uint2 pk; pk.x = f2bf2(v0, v1); pk.y = f2bf2(v2, v3);
        *(uint2*)(hb + (oc0>>3)*16400 + pidx*16 + ((oc0&7)<<1)) = pk;
    }
    // zero border pixels (rows/cols 0 and 31), all 8 channel groups
    for (int u = t; u < 992; u += 512) {
        const int bp = u >> 3, c8 = u & 7;
        int pidx;
        if (bp < 32) pidx = bp;
        else if (bp < 64) pidx = 31*32 + (bp - 32);
        else if (bp < 94) pidx = (bp - 64 + 1)*32;
        else pidx = (bp - 94 + 1)*32 + 31;
        uint4 z; z.x = z.y = z.z = z.w = 0u;
        *(uint4*)(hb + c8*16400 + pidx*16) = z;
    }
}

// ---------------------------------------------------------------------------
// conv2 + GN2 + ReLU fused. h1pad -> h2pad [8 c8][289 pix(17x17)][16B]
// ---------------------------------------------------------------------------
#define CONV2_LDS 132480
__global__ __launch_bounds__(512, 1) void conv2_fused(
    const short* __restrict__ h1pad, const short* __restrict__ afc2,
    const float* __restrict__ bias,
    const float* __restrict__ g2w, const float* __restrict__ g2b,
    short* __restrict__ h2pad)
{
    extern __shared__ char smem[];
    char*  sin    = smem;                        // 131200
    float* gnred  = (float*)(smem + 131200);     // 128
    float* gnq    = (float*)(smem + 131712);     // 128
    float* s_mean = (float*)(smem + 132224);     // 32
    float* s_rstd = (float*)(smem + 132352);     // 32

    const int t = threadIdx.x, b = blockIdx.x;
    const int w = t >> 6, l = t & 63, lhi = (l >> 4) & 3, llo = l & 15;
    const int mt = w >> 1, half = w & 1;
    const int oc0 = mt*16 + lhi*4;

    {
        const uint4* src = (const uint4*)((const char*)h1pad + (size_t)b*131200);
        uint4* dst = (uint4*)sin;
        for (int i = t; i < 8200; i += 512) dst[i] = src[i];
    }
    bf16x8 aw[32];
    #pragma unroll
    for (int kt = 0; kt < 32; ++kt)
        aw[kt] = *(const bf16x8*)(afc2 + ((size_t)((mt*32 + kt)*64 + l))*8);
    f32x4 bia = *(const f32x4*)&bias[oc0];
    __syncthreads();

    f32x4 acc[8];
    #pragma unroll
    for (int i = 0; i < 8; ++i) acc[i] = (f32x4){0.f,0.f,0.f,0.f};

    #pragma unroll
    for (int i = 0; i < 8; ++i) {
        const int nt = half*8 + i;
        if (nt > 14) continue;
        const int n = nt*16 + llo;
        const int p = n < 225 ? n : 224;
        const int oy = p/15, ox = p%15;
        #pragma unroll
        for (int kt = 0; kt < 32; ++kt) {
            const int tap = kt >> 1;
            const int ky = tap >> 2, kx = tap & 3;
            const int pidx = (oy*2 + ky)*32 + (ox*2 + kx);
            const int c8 = (kt & 1)*4 + lhi;
            bf16x8 bb = *(const bf16x8*)(sin + c8*16400 + pidx*16);
            acc[i] = MFMA16(aw[kt], bb, acc[i]);
        }
    }

    float s[4] = {0,0,0,0}, q[4] = {0,0,0,0};
    #pragma unroll
    for (int i = 0; i < 8; ++i) {
        const int nt = half*8 + i;
        if (nt > 14) continue;
        const int n = nt*16 + llo;
        #pragma unroll
        for (int r = 0; r < 4; ++r) {
            float v = acc[i][r] + bia[r];
            acc[i][r] = v;
            if (n < 225) { s[r] += v; q[r] += v*v; }
        }
    }
    #pragma unroll
    for (int off = 1; off < 16; off <<= 1) {
        #pragma unroll
        for (int r = 0; r < 4; ++r) {
            s[r] += __shfl_xor(s[r], off);
            q[r] += __shfl_xor(q[r], off);
        }
    }
    if (llo == 0) {
        #pragma unroll
        for (int r = 0; r < 4; ++r) {
            gnred[w*16 + lhi*4 + r] = s[r];
            gnq[w*16 + lhi*4 + r]   = q[r];
        }
    }
    __syncthreads();
    if (t < 32) {
        const int oc = t*2;
        const int mtg = oc >> 4, lh = (oc >> 2) & 3, r0 = oc & 3;
        const int i0 = (mtg*2)*16 + lh*4 + r0;
        float ss = gnred[i0] + gnred[i0+1] + gnred[i0+16] + gnred[i0+17];
        float qq = gnq[i0]   + gnq[i0+1]   + gnq[i0+16]   + gnq[i0+17];
        float m = ss * (1.f/450.f);
        float var = qq * (1.f/450.f) - m*m;
        s_mean[t] = m; s_rstd[t] = rsqrtf(var + 1e-5f);
    }
    __syncthreads();

    const int g0 = oc0 >> 1;
    const float m0 = s_mean[g0],   rs0 = s_rstd[g0];
    const float m1 = s_mean[g0+1], rs1 = s_rstd[g0+1];
    const float w0 = g2w[oc0], w1v = g2w[oc0+1], w2v = g2w[oc0+2], w3v = g2w[oc0+3];
    const float b0 = g2b[oc0], b1v_ = g2b[oc0+1], b2v_ = g2b[oc0+2], b3v_ = g2b[oc0+3];
    char* hb2 = (char*)h2pad + (size_t)b*36992;

    #pragma unroll
    for (int i = 0; i < 8; ++i) {
        const int nt = half*8 + i;
        if (nt > 14) continue;
        const int n = nt*16 + llo;
        if (n >= 225) continue;
        const int pidx = (n/15 + 1)*17 + (n%15 + 1);
        float v0 = fmaxf((acc[i][0]-m0)*rs0*w0  + b0,   0.f);
        float v1 = fmaxf((acc[i][1]-m0)*rs0*w1v + b1v_, 0.f);
        float v2 = fmaxf((acc[i][2]-m1)*rs1*w2v + b2v_, 0.f);
        float v3 = fmaxf((acc[i][3]-m1)*rs1*w3v + b3v_, 0.f);
        uint2 pk; pk.x = f2bf2(v0, v1); pk.y = f2bf2(v2, v3);
        *(uint2*)(hb2 + (oc0>>3)*4624 + pidx*16 + ((oc0&7)<<1)) = pk;
    }
    if (t < 512) {
        const int bp = t >> 3, c8 = t & 7;
        int pidx;
        if (bp < 17) pidx = bp;
        else if (bp < 34) pidx = 16*17 + (bp - 17);
        else if (bp < 49) pidx = (bp - 34 + 1)*17;
        else pidx = (bp - 49 + 1)*17 + 16;
        uint4 z; z.x = z.y = z.z = z.w = 0u;
        *(uint4*)(hb2 + c8*4624 + pidx*16) = z;
    }
}

// ---------------------------------------------------------------------------
// conv3 MFMA -> y fp32 [64][49] linear
// ---------------------------------------------------------------------------
__global__ __launch_bounds__(512, 1) void conv3_mfma(
    const short* __restrict__ h2pad, const short* __restrict__ afc3,
    const float* __restrict__ bias, float* __restrict__ y)
{
    __shared__ __align__(16) char sin[36992];
    const int t = threadIdx.x, b = blockIdx.x;
    const int w = t >> 6, l = t & 63, lhi = (l >> 4) & 3, llo = l & 15;
    const int mt = w >> 1, half = w & 1;
    const int oc0 = mt*16 + lhi*4;

    {
        const uint4* src = (const uint4*)((const char*)h2pad + (size_t)b*36992);
        uint4* dst = (uint4*)sin;
        for (int i = t; i < 2312; i += 512) dst[i] = src[i];
    }
    bf16x8 aw[32];
    #pragma unroll
    for (int kt = 0; kt < 32; ++kt)
        aw[kt] = *(const bf16x8*)(afc3 + ((size_t)((mt*32 + kt)*64 + l))*8);
    f32x4 bia = *(const f32x4*)&bias[oc0];
    __syncthreads();

    f32x4 acc[2];
    acc[0] = (f32x4){0.f,0.f,0.f,0.f};
    acc[1] = (f32x4){0.f,0.f,0.f,0.f};
    #pragma unroll
    for (int i = 0; i < 2; ++i) {
        const int nt = half*2 + i;
        const int n = nt*16 + llo;
        const int p = n < 49 ? n : 48;
        const int oy = p/7, ox = p%7;
        #pragma unroll
        for (int kt = 0; kt < 32; ++kt) {
            const int tap = kt >> 1;
            const int ky = tap >> 2, kx = tap & 3;
            const int pidx = (oy*2 + ky)*17 + (ox*2 + kx);
            const int c8 = (kt & 1)*4 + lhi;
            bf16x8 bb = *(const bf16x8*)(sin + c8*4624 + pidx*16);
            acc[i] = MFMA16(aw[kt], bb, acc[i]);
        }
    }
    #pragma unroll
    for (int i = 0; i < 2; ++i) {
        const int n = (half*2 + i)*16 + llo;
        if (n < 49) {
            #pragma unroll
            for (int r = 0; r < 4; ++r)
                y[(size_t)b*NELEM + (oc0 + r)*49 + n] = acc[i][r] + bia[r];
        }
    }
}

// ---------------------------------------------------------------------------
// The whole ODE + head, one block per image.
// State layout: [32 groups][104 pad] f32 (bank-conflict-free).
// Act layout: [8 c8][81 pix][16B] bf16 (81 = 1 mod 8).
// ---------------------------------------------------------------------------
#define SGRP 104
#define KSTR 3328
#define ODE_LDS 115456
__global__ __launch_bounds__(512, 1) void ode_head(
    const float* __restrict__ yin,
    const short* __restrict__ af1, const short* __restrict__ af2,
    const float* __restrict__ stab1, const float* __restrict__ stab2,
    const float* __restrict__ b1v, const float* __restrict__ b2v,
    const float* __restrict__ oaw, const float* __restrict__ oab,
    const float* __restrict__ obw, const float* __restrict__ obb,
    const float* __restrict__ ocw, const float* __restrict__ ocb,
    const float* __restrict__ g3w, const float* __restrict__ g3b,
    const float* __restrict__ linw, const float* __restrict__ linb,
    float* __restrict__ out)
{
    extern __shared__ char smem[];
    float* y_l    = (float*)smem;                  // [32][104]
    float* kbuf   = (float*)(smem + 13312);        // 6 x [32][104]
    char*  act0   = smem + 93184;                  // 10368
    char*  act1   = smem + 103552;                 // 10368
    float* gnred  = (float*)(smem + 113920);       // 128
    float* soaw   = (float*)(smem + 114432);       // 64
    float* soab   = (float*)(smem + 114688);       // 64
    float* s_mean = (float*)(smem + 114944);       // 32
    float* s_rstd = (float*)(smem + 115072);       // 32
    float* s_cm   = (float*)(smem + 115200);       // 64

    const int t = threadIdx.x, b = blockIdx.x;
    const int w = t >> 6, l = t & 63, lhi = (l >> 4) & 3, llo = l & 15;
    const int mt = w >> 1;
    const int ntA = (w & 1)*2, ntB = ntA + 1;
    const int nA = ntA*16 + llo, nB = ntB*16 + llo;
    const bool vA = nA < 49, vB = nB < 49;
    const int pxA = d_sigma[nA], pxB = d_sigma[nB];     // model pixels
    const int paA = (pxA/7 + 1)*9 + (pxA%7 + 1);
    const int paB = (pxB/7 + 1)*9 + (pxB%7 + 1);
    const int oc0 = mt*16 + lhi*4;
    const int g16 = t >> 4, sub = t & 15;

    // ---- init: load y, zero act, stage params to LDS/regs ----
    for (int u = t; u < 3136; u += 512) {
        const int g = u / 98, e = u - g*98;
        y_l[g*SGRP + e] = yin[(size_t)b*NELEM + u];
    }
    for (int i = t; i < 5184; i += 512) ((unsigned*)act0)[i] = 0u;
    if (t < 64) { soaw[t] = oaw[t]; soab[t] = oab[t]; }

    float stabA1[4], stabB1[4], stabA2[4], stabB2[4];
    #pragma unroll
    for (int r = 0; r < 4; ++r) {
        stabA1[r] = stab1[(oc0 + r)*49 + pxA];
        stabB1[r] = stab1[(oc0 + r)*49 + pxB];
        stabA2[r] = stab2[(oc0 + r)*49 + pxA];
        stabB2[r] = stab2[(oc0 + r)*49 + pxB];
    }
    const f32x4 bia1 = *(const f32x4*)&b1v[oc0];
    const f32x4 bia2 = *(const f32x4*)&b2v[oc0];
    const f32x4 gwB = *(const f32x4*)&obw[oc0];
    const f32x4 gbB = *(const f32x4*)&obb[oc0];
    const f32x4 gwC = *(const f32x4*)&ocw[oc0];
    const f32x4 gbC = *(const f32x4*)&ocb[oc0];
    __syncthreads();

    const float hf  = (float)(1.0/6.0);
    const float C10 = (float)((1.0/6.0)*(1.0/5.0));
    const float C20 = (float)((1.0/6.0)*(3.0/40.0)),  C21 = (float)((1.0/6.0)*(9.0/40.0));
    const float C30 = (float)((1.0/6.0)*(44.0/45.0)), C31 = (float)((1.0/6.0)*(-56.0/15.0)), C32 = (float)((1.0/6.0)*(32.0/9.0));
    const float C40 = (float)((1.0/6.0)*(19372.0/6561.0)), C41 = (float)((1.0/6.0)*(-25360.0/2187.0)),
                C42 = (float)((1.0/6.0)*(64448.0/6561.0)), C43 = (float)((1.0/6.0)*(-212.0/729.0));
    const float C50 = (float)((1.0/6.0)*(9017.0/3168.0)), C51 = (float)((1.0/6.0)*(-355.0/33.0)),
                C52 = (float)((1.0/6.0)*(46732.0/5247.0)), C53 = (float)((1.0/6.0)*(49.0/176.0)),
                C54 = (float)((1.0/6.0)*(-5103.0/18656.0));
    const float B0 = (float)((1.0/6.0)*(35.0/384.0)), B2c = (float)((1.0/6.0)*(500.0/1113.0)),
                B3c = (float)((1.0/6.0)*(125.0/192.0)), B4c = (float)((1.0/6.0)*(-2187.0/6784.0)),
                B5c = (float)((1.0/6.0)*(11.0/84.0));

    for (int step = 0; step < 6; ++step) {
        const float t0 = (float)step * hf;
        for (int stage = 0; stage < 6; ++stage) {
            float cA=0.f, cB=0.f, cC=0.f, cD=0.f, cE=0.f, tf=0.f;
            if (stage == 1)      { cA=C10; tf = 0.2f; }
            else if (stage == 2) { cA=C20; cB=C21; tf = 0.3f; }
            else if (stage == 3) { cA=C30; cB=C31; cC=C32; tf = 0.8f; }
            else if (stage == 4) { cA=C40; cB=C41; cC=C42; cD=C43; tf = (float)(8.0/9.0); }
            else if (stage == 5) { cA=C50; cB=C51; cC=C52; cD=C53; cE=C54; tf = 1.f; }
            const float tval = t0 + hf*tf;

            // ---- phase 1: combine (vec4) + GN_oa stats in regs + act0 b16 write
            {
                const float* Yg = y_l + g16*SGRP;
                const float* Kg = kbuf + g16*SGRP;
                const int e0 = 4*sub;
                const int n1 = (sub < 8) ? 4 : ((sub == 8) ? 2 : 0);
                const int e1 = 64 + 4*sub;

                f32x4 va, vb = {0.f,0.f,0.f,0.f};
                {
                    f32x4 xv = *(const f32x4*)(Yg + e0);
                    if (stage > 0) xv += cA * *(const f32x4*)(Kg + 0*KSTR + e0);
                    if (stage > 1) xv += cB * *(const f32x4*)(Kg + 1*KSTR + e0);
                    if (stage > 2) xv += cC * *(const f32x4*)(Kg + 2*KSTR + e0);
                    if (stage > 3) xv += cD * *(const f32x4*)(Kg + 3*KSTR + e0);
                    if (stage > 4) xv += cE * *(const f32x4*)(Kg + 4*KSTR + e0);
                    va = xv;
                }
                if (n1 == 4) {
                    f32x4 xv = *(const f32x4*)(Yg + e1);
                    if (stage > 0) xv += cA * *(const f32x4*)(Kg + 0*KSTR + e1);
                    if (stage > 1) xv += cB * *(const f32x4*)(Kg + 1*KSTR + e1);
                    if (stage > 2) xv += cC * *(const f32x4*)(Kg + 2*KSTR + e1);
                    if (stage > 3) xv += cD * *(const f32x4*)(Kg + 3*KSTR + e1);
                    if (stage > 4) xv += cE * *(const f32x4*)(Kg + 4*KSTR + e1);
                    vb = xv;
                } else if (n1 == 2) {
                    float x0 = Yg[96], x1 = Yg[97];
                    if (stage > 0) { x0 = fmaf(cA, Kg[0*KSTR+96], x0); x1 = fmaf(cA, Kg[0*KSTR+97], x1); }
                    if (stage > 1) { x0 = fmaf(cB, Kg[1*KSTR+96], x0); x1 = fmaf(cB, Kg[1*KSTR+97], x1); }
                    if (stage > 2) { x0 = fmaf(cC, Kg[2*KSTR+96], x0); x1 = fmaf(cC, Kg[2*KSTR+97], x1); }
                    if (stage > 3) { x0 = fmaf(cD, Kg[3*KSTR+96], x0); x1 = fmaf(cD, Kg[3*KSTR+97], x1); }
                    if (stage > 4) { x0 = fmaf(cE, Kg[4*KSTR+96], x0); x1 = fmaf(cE, Kg[4*KSTR+97], x1); }
                    vb[0] = x0; vb[1] = x1;
                }

                float s = va[0]+va[1]+va[2]+va[3];
                float q = va[0]*va[0]+va[1]*va[1]+va[2]*va[2]+va[3]*va[3];
                if (n1 >= 2) { s += vb[0]+vb[1]; q += vb[0]*vb[0]+vb[1]*vb[1]; }
                if (n1 == 4) { s += vb[2]+vb[3]; q += vb[2]*vb[2]+vb[3]*vb[3]; }
                s += __shfl_xor(s, 1); q += __shfl_xor(q, 1);
                s += __shfl_xor(s, 2); q += __shfl_xor(q, 2);
                s += __shfl_xor(s, 4); q += __shfl_xor(q, 4);
                s += __shfl_xor(s, 8); q += __shfl_xor(q, 8);
                const float m = s * (1.f/98.f);
                const float rs = rsqrtf(q * (1.f/98.f) - m*m + 1e-5f);
                const float w0 = soaw[2*g16], w1s = soaw[2*g16+1];
                const float bb0 = soab[2*g16], bb1 = soab[2*g16+1];

                #pragma unroll
                for (int j2 = 0; j2 < 4; ++j2) {
                    const int e = e0 + j2;
                    const int odd = e >= 49 ? 1 : 0;
                    const int ch = 2*g16 + odd;
                    const int p = e - 49*odd;
                    float nv = fmaxf((va[j2] - m)*rs*(odd ? w1s : w0) + (odd ? bb1 : bb0), 0.f);
                    const int pa = (p/7 + 1)*9 + (p%7) + 1;
                    *(unsigned short*)(act0 + (ch>>3)*1296 + pa*16 + ((ch&7)<<1)) = f2bf(nv);
                }
                for (int j2 = 0; j2 < n1; ++j2) {
                    const int e = e1 + j2;
                    const int odd = e >= 49 ? 1 : 0;
                    const int ch = 2*g16 + odd;
                    const int p = e - 49*odd;
                    float nv = fmaxf((vb[j2] - m)*rs*(odd ? w1s : w0) + (odd ? bb1 : bb0), 0.f);
                    const int pa = (p/7 + 1)*9 + (p%7) + 1;
                    *(unsigned short*)(act0 + (ch>>3)*1296 + pa*16 + ((ch&7)<<1)) = f2bf(nv);
                }
            }
            __syncthreads();   // S1: act0 ready

            float v0[4], v1[4];
            // ---- conv1 MFMA ----
            {
                bf16x8 aw[18];
                #pragma unroll
                for (int kt = 0; kt < 18; ++kt)
                    aw[kt] = *(const bf16x8*)(af1 + ((size_t)(mt*18 + kt)*64 + l)*8);
                f32x4 acc0 = {0.f,0.f,0.f,0.f}, acc1 = {0.f,0.f,0.f,0.f};
                #pragma unroll
                for (int kt = 0; kt < 18; ++kt) {
                    const int tap = kt >> 1;
                    const int dB = ((tap/3 - 1)*9 + (tap%3 - 1))*16;
                    const int cb = ((kt & 1)*4 + lhi)*1296;
                    bf16x8 bb0 = *(const bf16x8*)(act0 + cb + paA*16 + dB);
                    bf16x8 bb1 = *(const bf16x8*)(act0 + cb + paB*16 + dB);
                    acc0 = MFMA16(aw[kt], bb0, acc0);
                    acc1 = MFMA16(aw[kt], bb1, acc1);
                }
                #pragma unroll
                for (int r = 0; r < 4; ++r) {
                    v0[r] = acc0[r] + bia1[r] + tval * stabA1[r];
                    v1[r] = acc1[r] + bia1[r] + tval * stabB1[r];
                }
            }
            // GN_ob: reduce + single-barrier stats
            {
                float s0=0.f,q0=0.f,s1=0.f,q1=0.f;
                if (vA) { s0 += v0[0]+v0[1]; q0 += v0[0]*v0[0]+v0[1]*v0[1];
                          s1 += v0[2]+v0[3]; q1 += v0[2]*v0[2]+v0[3]*v0[3]; }
                if (vB) { s0 += v1[0]+v1[1]; q0 += v1[0]*v1[0]+v1[1]*v1[1];
                          s1 += v1[2]+v1[3]; q1 += v1[2]*v1[2]+v1[3]*v1[3]; }
                #pragma unroll
                for (int off = 1; off < 16; off <<= 1) {
                    s0 += __shfl_xor(s0, off); q0 += __shfl_xor(q0, off);
                    s1 += __shfl_xor(s1, off); q1 += __shfl_xor(q1, off);
                }
                if (llo == 0) {
                    float* gp = gnred + w*16 + lhi*4;
                    gp[0]=s0; gp[1]=q0; gp[2]=s1; gp[3]=q1;
                }
            }
            __syncthreads();   // S2: gnred ready
            {
                const int gb = mt*32 + lhi*4;
                const float sg0 = gnred[gb]   + gnred[gb+16];
                const float qg0 = gnred[gb+1] + gnred[gb+17];
                const float sg1 = gnred[gb+2] + gnred[gb+18];
                const float qg1 = gnred[gb+3] + gnred[gb+19];
                const float m0 = sg0*(1.f/98.f);
                const float r0 = rsqrtf(qg0*(1.f/98.f) - m0*m0 + 1e-5f);
                const float m1 = sg1*(1.f/98.f);
                const float r1 = rsqrtf(qg1*(1.f/98.f) - m1*m1 + 1e-5f);
                v0[0] = fmaxf((v0[0]-m0)*r0*gwB[0]+gbB[0], 0.f);
                v0[1] = fmaxf((v0[1]-m0)*r0*gwB[1]+gbB[1], 0.f);
                v0[2] = fmaxf((v0[2]-m1)*r1*gwB[2]+gbB[2], 0.f);
                v0[3] = fmaxf((v0[3]-m1)*r1*gwB[3]+gbB[3], 0.f);
                v1[0] = fmaxf((v1[0]-m0)*r0*gwB[0]+gbB[0], 0.f);
                v1[1] = fmaxf((v1[1]-m0)*r0*gwB[1]+gbB[1], 0.f);
                v1[2] = fmaxf((v1[2]-m1)*r1*gwB[2]+gbB[2], 0.f);
                v1[3] = fmaxf((v1[3]-m1)*r1*gwB[3]+gbB[3], 0.f);
                if (vA) {
                    uint2 pk; pk.x = f2bf2(v0[0], v0[1]); pk.y = f2bf2(v0[2], v0[3]);
                    *(uint2*)(act1 + (oc0>>3)*1296 + paA*16 + ((oc0&7)<<1)) = pk;
                }
                if (vB) {
                    uint2 pk; pk.x = f2bf2(v1[0], v1[1]); pk.y = f2bf2(v1[2], v1[3]);
                    *(uint2*)(act1 + (oc0>>3)*1296 + paB*16 + ((oc0&7)<<1)) = pk;
                }
            }
            __syncthreads();   // S3: act1 ready

            // ---- conv2 MFMA ----
            {
                bf16x8 aw[18];
                #pragma unroll
                for (int kt = 0; kt < 18; ++kt)
                    aw[kt] = *(const bf16x8*)(af2 + ((size_t)(mt*18 + kt)*64 + l)*8);
                f32x4 acc0 = {0.f,0.f,0.f,0.f}, acc1 = {0.f,0.f,0.f,0.f};
                #pragma unroll
                for (int kt = 0; kt < 18; ++kt) {
                    const int tap = kt >> 1;
                    const int dB = ((tap/3 - 1)*9 + (tap%3 - 1))*16;
                    const int cb = ((kt & 1)*4 + lhi)*1296;
                    bf16x8 bb0 = *(const bf16x8*)(act1 + cb + paA*16 + dB);
                    bf16x8 bb1 = *(const bf16x8*)(act1 + cb + paB*16 + dB);
                    acc0 = MFMA16(aw[kt], bb0, acc0);
                    acc1 = MFMA16(aw[kt], bb1, acc1);
                }
                #pragma unroll
                for (int r = 0; r < 4; ++r) {
                    v0[r] = acc0[r] + bia2[r] + tval * stabA2[r];
                    v1[r] = acc1[r] + bia2[r] + tval * stabB2[r];
                }
            }
            {
                float s0=0.f,q0=0.f,s1=0.f,q1=0.f;
                if (vA) { s0 += v0[0]+v0[1]; q0 += v0[0]*v0[0]+v0[1]*v0[1];
                          s1 += v0[2]+v0[3]; q1 += v0[2]*v0[2]+v0[3]*v0[3]; }
                if (vB) { s0 += v1[0]+v1[1]; q0 += v1[0]*v1[0]+v1[1]*v1[1];
                          s1 += v1[2]+v1[3]; q1 += v1[2]*v1[2]+v1[3]*v1[3]; }
                #pragma unroll
                for (int off = 1; off < 16; off <<= 1) {
                    s0 += __shfl_xor(s0, off); q0 += __shfl_xor(q0, off);
                    s1 += __shfl_xor(s1, off); q1 += __shfl_xor(q1, off);
                }
                if (llo == 0) {
                    float* gp = gnred + w*16 + lhi*4;
                    gp[0]=s0; gp[1]=q0; gp[2]=s1; gp[3]=q1;
                }
            }
            __syncthreads();   // S4: gnred ready
            {
                const int gb = mt*32 + lhi*4;
                const float sg0 = gnred[gb]   + gnred[gb+16];
                const float qg0 = gnred[gb+1] + gnred[gb+17];
                const float sg1 = gnred[gb+2] + gnred[gb+18];
                const float qg1 = gnred[gb+3] + gnred[gb+19];
                const float m0 = sg0*(1.f/98.f);
                const float r0 = rsqrtf(qg0*(1.f/98.f) - m0*m0 + 1e-5f);
                const float m1 = sg1*(1.f/98.f);
                const float r1 = rsqrtf(qg1*(1.f/98.f) - m1*m1 + 1e-5f);
                float* kd = kbuf + stage*KSTR;
                const int gA = oc0 >> 1;
                if (vA) {
                    kd[gA*SGRP + pxA]            = (v0[0]-m0)*r0*gwC[0]+gbC[0];
                    kd[gA*SGRP + 49 + pxA]       = (v0[1]-m0)*r0*gwC[1]+gbC[1];
                    kd[(gA+1)*SGRP + pxA]        = (v0[2]-m1)*r1*gwC[2]+gbC[2];
                    kd[(gA+1)*SGRP + 49 + pxA]   = (v0[3]-m1)*r1*gwC[3]+gbC[3];
                }
                if (vB) {
                    kd[gA*SGRP + pxB]            = (v1[0]-m0)*r0*gwC[0]+gbC[0];
                    kd[gA*SGRP + 49 + pxB]       = (v1[1]-m0)*r0*gwC[1]+gbC[1];
                    kd[(gA+1)*SGRP + pxB]        = (v1[2]-m1)*r1*gwC[2]+gbC[2];
                    kd[(gA+1)*SGRP + 49 + pxB]   = (v1[3]-m1)*r1*gwC[3]+gbC[3];
                }
            }
            __syncthreads();   // S5: k ready

            if (stage == 5) {
                float* Yg = y_l + g16*SGRP;
                const float* Kg = kbuf + g16*SGRP;
                const int e0 = 4*sub;
                {
                    f32x4 v = *(const f32x4*)(Yg + e0);
                    v += B0  * *(const f32x4*)(Kg + 0*KSTR + e0);
                    v += B2c * *(const f32x4*)(Kg + 2*KSTR + e0);
                    v += B3c * *(const f32x4*)(Kg + 3*KSTR + e0);
                    v += B4c * *(const f32x4*)(Kg + 4*KSTR + e0);
                    v += B5c * *(const f32x4*)(Kg + 5*KSTR + e0);
                    *(f32x4*)(Yg + e0) = v;
                }
                if (sub < 8) {
                    const int e1 = 64 + 4*sub;
                    f32x4 v = *(const f32x4*)(Yg + e1);
                    v += B0  * *(const f32x4*)(Kg + 0*KSTR + e1);
                    v += B2c * *(const f32x4*)(Kg + 2*KSTR + e1);
                    v += B3c * *(const f32x4*)(Kg + 3*KSTR + e1);
                    v += B4c * *(const f32x4*)(Kg + 4*KSTR + e1);
                    v += B5c * *(const f32x4*)(Kg + 5*KSTR + e1);
                    *(f32x4*)(Yg + e1) = v;
                } else if (sub == 8) {
                    #pragma unroll
                    for (int j2 = 0; j2 < 2; ++j2) {
                        const int e = 96 + j2;
                        float v = Yg[e];
                        v = fmaf(B0,  Kg[0*KSTR+e], v);
                        v = fmaf(B2c, Kg[2*KSTR+e], v);
                        v = fmaf(B3c, Kg[3*KSTR+e], v);
                        v = fmaf(B4c, Kg[4*KSTR+e], v);
                        v = fmaf(B5c, Kg[5*KSTR+e], v);
                        Yg[e] = v;
                    }
                }
                __syncthreads();   // S6: y updated
            }
        }
    }

    // ---- head: GN(g3)+ReLU -> spatial mean -> linear ----
    {
        float s = 0.f, q = 0.f;
        const float* Yg = y_l + g16*SGRP;
        for (int e = sub; e < 98; e += 16) {
            float v = Yg[e];
            s += v; q += v*v;
        }
        s += __shfl_xor(s,1); q += __shfl_xor(q,1);
        s += __shfl_xor(s,2); q += __shfl_xor(q,2);
        s += __shfl_xor(s,4); q += __shfl_xor(q,4);
        s += __shfl_xor(s,8); q += __shfl_xor(q,8);
        if (sub == 0) {
            float m = s * (1.f/98.f);
            float var = q * (1.f/98.f) - m*m;
            s_mean[g16] = m; s_rstd[g16] = rsqrtf(var + 1e-5f);
        }
    }
    __syncthreads();
    if (t < 64) {
        const int ch = t, g = ch >> 1;
        const float m = s_mean[g], r = s_rstd[g];
        const float ww = g3w[ch], bb = g3b[ch];
        const float* Yc = y_l + g*SGRP + (ch & 1)*49;
        float sum = 0.f;
        for (int p = 0; p < 49; ++p) {
            float v = (Yc[p] - m)*r*ww + bb;
            sum += fmaxf(v, 0.f);
        }
        s_cm[ch] = sum * (1.f/49.f);
    }
    __syncthreads();
    if (t < 10) {
        float a = linb[t];
        for (int c = 0; c < 64; ++c) a = fmaf(s_cm[c], linw[t*64 + c], a);
        out[b*10 + t] = a;
    }
}

// ---------------------------------------------------------------------------
// Host launch
// ---------------------------------------------------------------------------
extern "C" void kernel_launch(void* const* d_in, const int* in_sizes, int n_in,
                              void* d_out, int out_size, void* d_ws, size_t ws_size,
                              hipStream_t stream)
{
    const float* x      = (const float*)d_in[0];
    const float* c1_w   = (const float*)d_in[1];
    const float* c1_b   = (const float*)d_in[2];
    const float* g1_w   = (const float*)d_in[3];
    const float* g1_b   = (const float*)d_in[4];
    const float* c2_w   = (const float*)d_in[5];
    const float* c2_b   = (const float*)d_in[6];
    const float* g2_w   = (const float*)d_in[7];
    const float* g2_b   = (const float*)d_in[8];
    const float* c3_w   = (const float*)d_in[9];
    const float* c3_b   = (const float*)d_in[10];
    const float* oa_w   = (const float*)d_in[11];
    const float* oa_b   = (const float*)d_in[12];
    const float* occ1_w = (const float*)d_in[13];
    const float* occ1_b = (const float*)d_in[14];
    const float* ob_w   = (const float*)d_in[15];
    const float* ob_b   = (const float*)d_in[16];
    const float* occ2_w = (const float*)d_in[17];
    const float* occ2_b = (const float*)d_in[18];
    const float* oc_w   = (const float*)d_in[19];
    const float* oc_b   = (const float*)d_in[20];
    const float* g3_w   = (const float*)d_in[21];
    const float* g3_b   = (const float*)d_in[22];
    const float* lin_w  = (const float*)d_in[23];
    const float* lin_b  = (const float*)d_in[24];
    float* out = (float*)d_out;

    float* ws = (float*)d_ws;
    size_t off = 0;
    float* y     = ws + off; off += 802816;
    float* stab1 = ws + off; off += 3136;
    float* stab2 = ws + off; off += 3136;
    short* af1   = (short*)(ws + off); off += 18432;    // 36864 shorts
    short* af2   = (short*)(ws + off); off += 18432;
    short* afc1  = (short*)(ws + off); off += 1024;     // 2048 shorts
    short* afc2  = (short*)(ws + off); off += 32768;    // 65536 shorts
    short* afc3  = (short*)(ws + off); off += 32768;
    short* h1pad = (short*)(ws + off); off += 8396800;  // 256*65600 shorts
    short* h2pad = (short*)(ws + off); off += 2367488;  // 256*18496 shorts

    // prep (weights constant per launch)
    prep_afrag_kernel<<<dim3(144, 2), 256, 0, stream>>>(occ1_w, occ2_w, af1, af2);
    prep_stab_kernel<<<dim3(13, 2), 256, 0, stream>>>(occ1_w, occ2_w, stab1, stab2);
    prep_c1frag_kernel<<<8, 256, 0, stream>>>(c1_w, afc1);
    prep_c23frag_kernel<<<dim3(256, 2), 256, 0, stream>>>(c2_w, c3_w, afc2, afc3);

    // preamble CNN (fused, per-image MFMA)
    conv1_fused<<<B, 512, 0, stream>>>(x, afc1, c1_b, g1_w, g1_b, h1pad);
    conv2_fused<<<B, 512, CONV2_LDS, stream>>>(h1pad, afc2, c2_b, g2_w, g2_b, h2pad);
    conv3_mfma<<<B, 512, 0, stream>>>(h2pad, afc3, c3_b, y);

    // full ODE + head, one launch
    ode_head<<<B, 512, ODE_LDS, stream>>>(y, af1, af2, stab1, stab2,
        occ1_b, occ2_b, oa_w, oa_b, ob_w, ob_b, oc_w, oc_b,
        g3_w, g3_b, lin_w, lin_b, out);
}